// Round 7
// baseline (133.297 us; speedup 1.0000x reference)
//
#include <hip/hip_runtime.h>
#include <math.h>

typedef short bf16x8 __attribute__((ext_vector_type(8)));
typedef float f32x4 __attribute__((ext_vector_type(4)));
typedef float f32x16 __attribute__((ext_vector_type(16)));
typedef int int2v __attribute__((ext_vector_type(2)));

constexpr int Bc = 2, Tc = 2048, Cc = 1024, Hc = 16, Dc = 64;
constexpr int Mc = Bc * Tc;  // 4096

#if __has_builtin(__builtin_amdgcn_exp2f)
#define EXP2(x) __builtin_amdgcn_exp2f(x)
#else
#define EXP2(x) exp2f(x)
#endif

#define SBAR() do { asm volatile("" ::: "memory"); \
                    __builtin_amdgcn_s_barrier();   \
                    asm volatile("" ::: "memory"); } while (0)

__device__ __forceinline__ unsigned short f2bf(float f) {
    union { float f; unsigned u; } v; v.f = f;
    unsigned r = v.u + 0x7fffu + ((v.u >> 16) & 1u);  // RNE
    return (unsigned short)(r >> 16);
}

__device__ __forceinline__ float bf2f(unsigned short u) {
    union { unsigned u; float f; } v; v.u = (unsigned)u << 16; return v.f;
}

__device__ __forceinline__ unsigned cvt_pk_bf16(float lo, float hi) {
    unsigned r;
    asm("v_cvt_pk_bf16_f32 %0, %1, %2" : "=v"(r) : "v"(lo), "v"(hi));
    return r;
}

__device__ __forceinline__ void gload16(const void* g, void* l) {
    __builtin_amdgcn_global_load_lds(
        (const __attribute__((address_space(1))) void*)g,
        (__attribute__((address_space(3))) void*)l, 16, 0, 0);
}

// ---------------------------------------------------------------------------
__global__ __launch_bounds__(256)
void cast_bf16(const float* __restrict__ in, unsigned short* __restrict__ out, int n8) {
    int i = blockIdx.x * 256 + threadIdx.x;
    if (i >= n8) return;
    const float4* p = (const float4*)in;
    float4 a = p[i * 2], b = p[i * 2 + 1];
    union { unsigned short u[8]; bf16x8 v; } r;
    r.u[0] = f2bf(a.x); r.u[1] = f2bf(a.y); r.u[2] = f2bf(a.z); r.u[3] = f2bf(a.w);
    r.u[4] = f2bf(b.x); r.u[5] = f2bf(b.y); r.u[6] = f2bf(b.z); r.u[7] = f2bf(b.w);
    *(bf16x8*)(out + i * 8) = r.v;
}

__global__ __launch_bounds__(256)
void cast_w4(const float* __restrict__ a, const float* __restrict__ b,
             const float* __restrict__ c, const float* __restrict__ d,
             unsigned short* __restrict__ oa, unsigned short* __restrict__ ob,
             unsigned short* __restrict__ oc, unsigned short* __restrict__ od) {
    const float* src = blockIdx.y == 0 ? a : blockIdx.y == 1 ? b : blockIdx.y == 2 ? c : d;
    unsigned short* dst = blockIdx.y == 0 ? oa : blockIdx.y == 1 ? ob : blockIdx.y == 2 ? oc : od;
    int i = blockIdx.x * 256 + threadIdx.x;
    const float4* p = (const float4*)src;
    float4 x = p[i * 2], y = p[i * 2 + 1];
    union { unsigned short u[8]; bf16x8 v; } r;
    r.u[0] = f2bf(x.x); r.u[1] = f2bf(x.y); r.u[2] = f2bf(x.z); r.u[3] = f2bf(x.w);
    r.u[4] = f2bf(y.x); r.u[5] = f2bf(y.y); r.u[6] = f2bf(y.z); r.u[7] = f2bf(y.w);
    *(bf16x8*)(dst + i * 8) = r.v;
}

// ---------------------------------------------------------------------------
// Fused QKV GEMM (NT): 128x64 tile, BK=32, 4 waves (2Mx2N), 1536 blocks
// (6/CU, 24 waves/CU) -- TLP-first; proven single-buffer 2-barrier loop.
// blockIdx.y: seg = y>>4 (0=Q 1=K 2=V), n0 = (y&15)*64.
// ---------------------------------------------------------------------------
__global__ __launch_bounds__(256)
void gemm_qkv(const unsigned short* __restrict__ A,
              const unsigned short* __restrict__ Wq,
              const unsigned short* __restrict__ Wk,
              const unsigned short* __restrict__ Wv,
              unsigned short* __restrict__ Qo,
              unsigned short* __restrict__ Ko,
              unsigned short* __restrict__ Vo) {
    __shared__ unsigned short As[128 * 32];
    __shared__ unsigned short Bs[64 * 32];
    const int t = threadIdx.x;
    const int lane = t & 63, l15 = lane & 15, l4 = lane >> 4;
    const int w = t >> 6, wr = w >> 1, wc = w & 1;
    const int seg = blockIdx.y >> 4;              // 0=Q 1=K 2=V
    const unsigned short* W = seg == 0 ? Wq : seg == 1 ? Wk : Wv;
    const int m0 = blockIdx.x * 128, n0 = (blockIdx.y & 15) * 64;

    f32x4 acc[4][2] = {};

    for (int k0 = 0; k0 < Cc; k0 += 32) {
        __syncthreads();
        #pragma unroll
        for (int it = 0; it < 2; ++it) {
            int c = t + it * 256;
            int row = c >> 2, ko = (c & 3) << 3;
            gload16(A + (size_t)(m0 + row) * Cc + k0 + ko, As + c * 8);
        }
        {
            int row = t >> 2, ko = (t & 3) << 3;
            gload16(W + (size_t)(n0 + row) * Cc + k0 + ko, Bs + t * 8);
        }
        __syncthreads();
        bf16x8 af[4], bfr[2];
        #pragma unroll
        for (int i = 0; i < 4; ++i)
            af[i] = *(const bf16x8*)(As + ((wr * 64 + i * 16 + l15) * 32 + l4 * 8));
        #pragma unroll
        for (int j = 0; j < 2; ++j)
            bfr[j] = *(const bf16x8*)(Bs + ((wc * 32 + j * 16 + l15) * 32 + l4 * 8));
        #pragma unroll
        for (int i = 0; i < 4; ++i)
            #pragma unroll
            for (int j = 0; j < 2; ++j)
                acc[i][j] = __builtin_amdgcn_mfma_f32_16x16x32_bf16(af[i], bfr[j], acc[i][j], 0, 0, 0);
    }

    const float qscale = 0.18033688011112042f;  // 0.125 * log2(e)
    const int r0 = wr * 64 + (l4 << 2);
    const int c0 = wc * 32 + l15;
    #pragma unroll
    for (int i = 0; i < 4; ++i)
        #pragma unroll
        for (int j = 0; j < 2; ++j)
            #pragma unroll
            for (int r = 0; r < 4; ++r) {
                int row = m0 + r0 + i * 16 + r;
                int col = n0 + c0 + j * 16;
                float v = acc[i][j][r];
                int bb = row >> 11, tt = row & (Tc - 1);
                int hh = col >> 6, dd = col & 63;
                if (seg == 0)
                    Qo[((((size_t)bb * Hc + hh) * Tc + tt) << 6) + dd] = f2bf(v * qscale);
                else if (seg == 1)
                    Ko[((((size_t)bb * Hc + hh) * Tc + tt) << 6) + dd] = f2bf(v);
                else
                    Vo[(((size_t)bb * Hc + hh) * Dc + dd) * Tc + tt] = f2bf(v);
            }
}

// ---------------------------------------------------------------------------
// Out-projection GEMM (NT): 64x64 tile, 1024 blocks (4/CU), fp32 out [M,C].
// ---------------------------------------------------------------------------
__global__ __launch_bounds__(256)
void gemm_out(const unsigned short* __restrict__ A,
              const unsigned short* __restrict__ W,
              float* __restrict__ outp) {
    __shared__ unsigned short As[64 * 32];
    __shared__ unsigned short Bs[64 * 32];
    const int t = threadIdx.x;
    const int lane = t & 63, l15 = lane & 15, l4 = lane >> 4;
    const int w = t >> 6, wr = w >> 1, wc = w & 1;
    const int m0 = blockIdx.x * 64, n0 = blockIdx.y * 64;

    f32x4 acc[2][2] = {};

    for (int k0 = 0; k0 < Cc; k0 += 32) {
        __syncthreads();
        {
            int row = t >> 2, ko = (t & 3) << 3;
            gload16(A + (size_t)(m0 + row) * Cc + k0 + ko, As + t * 8);
            gload16(W + (size_t)(n0 + row) * Cc + k0 + ko, Bs + t * 8);
        }
        __syncthreads();
        bf16x8 af[2], bfr[2];
        #pragma unroll
        for (int i = 0; i < 2; ++i)
            af[i] = *(const bf16x8*)(As + ((wr * 32 + i * 16 + l15) * 32 + l4 * 8));
        #pragma unroll
        for (int j = 0; j < 2; ++j)
            bfr[j] = *(const bf16x8*)(Bs + ((wc * 32 + j * 16 + l15) * 32 + l4 * 8));
        #pragma unroll
        for (int i = 0; i < 2; ++i)
            #pragma unroll
            for (int j = 0; j < 2; ++j)
                acc[i][j] = __builtin_amdgcn_mfma_f32_16x16x32_bf16(af[i], bfr[j], acc[i][j], 0, 0, 0);
    }

    const int r0 = wr * 32 + (l4 << 2);
    const int c0 = wc * 32 + l15;
    #pragma unroll
    for (int i = 0; i < 2; ++i)
        #pragma unroll
        for (int j = 0; j < 2; ++j)
            #pragma unroll
            for (int r = 0; r < 4; ++r)
                outp[(size_t)(m0 + r0 + i * 16 + r) * Cc + n0 + c0 + j * 16] = acc[i][j][r];
}

// ---------------------------------------------------------------------------
// MFMA causal flash attention, split-K, counted-vmcnt double-buffer pipeline.
// 64 q-rows per block (2 waves x 32). Job: bit7=split, bit6=half, bits4..0=c.
// ---------------------------------------------------------------------------
__device__ __constant__ unsigned char JOBS[48] = {
    159, 223, 222, 15, 158, 157, 221, 220, 14, 156,
    155, 219, 218, 13, 154, 153, 217, 216, 12, 152,
    151, 215, 214, 11, 150, 149, 213, 212, 10, 148,
    147, 211, 210,  9, 146, 145, 209, 208,  8, 144,
      7,   6,   5,  4,   3,   2,   1,   0
};

__global__ __launch_bounds__(128)
void attn_mfma(const unsigned short* __restrict__ Q,
               const unsigned short* __restrict__ K,
               const unsigned short* __restrict__ Vt,
               unsigned short* __restrict__ Y,
               unsigned short* __restrict__ P1,   // half1 partial O
               float* __restrict__ mlf) {         // m0[32768], l0, m1, l1
    __shared__ unsigned short Ks[2][64 * 64];  // [buf][key][d]   (swizzled)
    __shared__ unsigned short Vs[2][64 * 64];  // [buf][d][key]   (swizzled)

    const int t = threadIdx.x, lane = t & 63, w = t >> 6;
    const int l31 = lane & 31, h = lane >> 5;
    const int bh = blockIdx.x;
    const int bb = bh >> 4, hh = bh & 15;

    const unsigned char job = JOBS[blockIdx.y];
    const int c = job & 31;
    const bool split = job & 128;
    const int half = (job >> 6) & 1;
    const int ntile = c + 1, smid = ntile >> 1;
    const int kb0 = (split && half) ? smid : 0;
    const int kb1 = (split && !half) ? smid : ntile;

    const int qbase = c * 64 + w * 32;
    const int q = qbase + l31;

    const unsigned short* Qp = Q + (size_t)bh * Tc * Dc;
    const unsigned short* Kp = K + (size_t)bh * Tc * Dc;
    const unsigned short* Vp = Vt + (size_t)bh * Dc * Tc;

    // Q as B-operand: col=q=lane&31, k = kc*16 + h*8 + j  (pre-scaled by 0.125*log2e)
    bf16x8 qf[4];
    #pragma unroll
    for (int kc = 0; kc < 4; ++kc)
        qf[kc] = *(const bf16x8*)(Qp + (size_t)q * 64 + kc * 16 + h * 8);

    f32x16 ot[2] = {};          // O^T: rows d=dt*32+(r&3)+8*(r>>2)+4h, col q
    float m = -INFINITY, lsum = 0.f;

    auto stage = [&](int kb, int buf) {
        #pragma unroll
        for (int it = 0; it < 4; ++it) {
            int idx = t + it * 128;
            int row = idx >> 3, slot = idx & 7;
            int ss = slot ^ (row & 7);  // pre-swizzled source
            gload16(Kp + (size_t)(kb * 64 + row) * 64 + ss * 8, &Ks[buf][idx * 8]);
            gload16(Vp + (size_t)row * Tc + kb * 64 + ss * 8, &Vs[buf][idx * 8]);
        }
    };

    stage(kb0, 0);
    if (kb0 + 1 < kb1) stage(kb0 + 1, 1);

    for (int kb = kb0; kb < kb1; ++kb) {
        const int cur = (kb - kb0) & 1;
        // counted wait: stage(kb) complete, stage(kb+1)'s 8 loads stay in flight
        if (kb + 1 < kb1) asm volatile("s_waitcnt vmcnt(8)" ::: "memory");
        else              asm volatile("s_waitcnt vmcnt(0)" ::: "memory");
        SBAR();

        // ---- S^T = K @ Q^T  (log2 domain; 2 key-tiles of 32) ----
        f32x16 st[2] = {};
        __builtin_amdgcn_s_setprio(1);
        #pragma unroll
        for (int nt = 0; nt < 2; ++nt) {
            int key = nt * 32 + l31;
            #pragma unroll
            for (int kc = 0; kc < 4; ++kc) {
                int boff = (kc * 32 + h * 16) ^ ((key & 7) << 4);
                bf16x8 kf = *(const bf16x8*)(&Ks[cur][((key << 7) + boff) >> 1]);
                st[nt] = __builtin_amdgcn_mfma_f32_32x32x16_bf16(kf, qf[kc], st[nt], 0, 0, 0);
            }
        }
        __builtin_amdgcn_s_setprio(0);

        if (kb * 64 + 63 > qbase) {  // causal mask (diagonal tile only)
            #pragma unroll
            for (int nt = 0; nt < 2; ++nt)
                #pragma unroll
                for (int r = 0; r < 16; ++r) {
                    int key = kb * 64 + nt * 32 + (r & 3) + 8 * (r >> 2) + 4 * h;
                    if (key > q) st[nt][r] = -1e30f;
                }
        }

        // ---- lane-local row max ----
        float mx[16];
        #pragma unroll
        for (int r = 0; r < 16; ++r) mx[r] = fmaxf(st[0][r], st[1][r]);
        #pragma unroll
        for (int s2 = 8; s2 > 0; s2 >>= 1)
            #pragma unroll
            for (int r = 0; r < s2; ++r) mx[r] = fmaxf(mx[r], mx[r + s2]);
        float tmax = fmaxf(mx[0], __shfl_xor(mx[0], 32));

        // ---- defer-max (T13) ----
        if (__any(tmax > m + 8.f)) {
            float mn = fmaxf(m, tmax);
            float al = EXP2(m - mn);
            m = mn;
            lsum *= al;
            #pragma unroll
            for (int dt = 0; dt < 2; ++dt)
                #pragma unroll
                for (int r = 0; r < 16; ++r) ot[dt][r] *= al;
        }

        float psa[4] = {0.f, 0.f, 0.f, 0.f};
        #pragma unroll
        for (int nt = 0; nt < 2; ++nt)
            #pragma unroll
            for (int r = 0; r < 16; ++r) {
                float p = EXP2(st[nt][r] - m);
                st[nt][r] = p;
                psa[r & 3] += p;
            }
        lsum += (psa[0] + psa[1]) + (psa[2] + psa[3]);

        // ---- P^T -> bf16 B-frags in-register (T12), then PV ----
        #pragma unroll
        for (int nt = 0; nt < 2; ++nt) {
            unsigned a0 = cvt_pk_bf16(st[nt][0],  st[nt][1]);
            unsigned b0 = cvt_pk_bf16(st[nt][4],  st[nt][5]);
            unsigned a1 = cvt_pk_bf16(st[nt][2],  st[nt][3]);
            unsigned b1 = cvt_pk_bf16(st[nt][6],  st[nt][7]);
            int2v r0 = __builtin_amdgcn_permlane32_swap((int)a0, (int)b0, false, false);
            int2v r1 = __builtin_amdgcn_permlane32_swap((int)a1, (int)b1, false, false);
            union { unsigned u[4]; bf16x8 v; } pf0, pf1;
            pf0.u[0] = r0.x; pf0.u[1] = r1.x; pf0.u[2] = r0.y; pf0.u[3] = r1.y;
            unsigned c0 = cvt_pk_bf16(st[nt][8],  st[nt][9]);
            unsigned d0 = cvt_pk_bf16(st[nt][12], st[nt][13]);
            unsigned c1 = cvt_pk_bf16(st[nt][10], st[nt][11]);
            unsigned d1 = cvt_pk_bf16(st[nt][14], st[nt][15]);
            int2v r2 = __builtin_amdgcn_permlane32_swap((int)c0, (int)d0, false, false);
            int2v r3 = __builtin_amdgcn_permlane32_swap((int)c1, (int)d1, false, false);
            pf1.u[0] = r2.x; pf1.u[1] = r3.x; pf1.u[2] = r2.y; pf1.u[3] = r3.y;

            __builtin_amdgcn_s_setprio(1);
            #pragma unroll
            for (int dt = 0; dt < 2; ++dt) {
                int d = dt * 32 + l31;
                int v0off = (nt * 64 + h * 16) ^ ((d & 7) << 4);
                bf16x8 vf0 = *(const bf16x8*)(&Vs[cur][((d << 7) + v0off) >> 1]);
                ot[dt] = __builtin_amdgcn_mfma_f32_32x32x16_bf16(vf0, pf0.v, ot[dt], 0, 0, 0);
            }
            #pragma unroll
            for (int dt = 0; dt < 2; ++dt) {
                int d = dt * 32 + l31;
                int v1off = (nt * 64 + 32 + h * 16) ^ ((d & 7) << 4);
                bf16x8 vf1 = *(const bf16x8*)(&Vs[cur][((d << 7) + v1off) >> 1]);
                ot[dt] = __builtin_amdgcn_mfma_f32_32x32x16_bf16(vf1, pf1.v, ot[dt], 0, 0, 0);
            }
            __builtin_amdgcn_s_setprio(0);
        }

        SBAR();                     // all waves done reading buf cur
        if (kb + 2 < kb1) stage(kb + 2, cur);
    }

    // ---- epilogue ----
    float lf = lsum + __shfl_xor(lsum, 32);
    unsigned short* dst = (split && half) ? P1 : Y;
    float inv = split ? 1.f : 1.f / lf;
    size_t base = ((size_t)bb * Tc + q) * Cc + hh * 64;
    #pragma unroll
    for (int dt = 0; dt < 2; ++dt)
        #pragma unroll
        for (int rg = 0; rg < 4; ++rg) {
            int d0 = dt * 32 + rg * 8 + 4 * h;
            ushort4 s4;
            s4.x = f2bf(ot[dt][rg * 4 + 0] * inv);
            s4.y = f2bf(ot[dt][rg * 4 + 1] * inv);
            s4.z = f2bf(ot[dt][rg * 4 + 2] * inv);
            s4.w = f2bf(ot[dt][rg * 4 + 3] * inv);
            *(ushort4*)(dst + base + d0) = s4;
        }
    if (split && h == 0) {
        int ridx = bh * 1024 + (q - 1024);
        mlf[ridx + (half ? 65536 : 0)]     = m;   // m
        mlf[ridx + (half ? 98304 : 32768)] = lf;  // l
    }
}

// ---------------------------------------------------------------------------
__global__ __launch_bounds__(256)
void attn_combine(unsigned short* __restrict__ Y,
                  const unsigned short* __restrict__ P1,
                  const float* __restrict__ mlf) {
    int tid = blockIdx.x * 256 + threadIdx.x;   // 0 .. 262143
    int ridx = tid >> 3;
    int d0 = (tid & 7) * 8;
    int bh = ridx >> 10, qq = ridx & 1023;
    int bb = bh >> 4, hh = bh & 15;
    int q = 1024 + qq;
    size_t off = ((size_t)bb * Tc + q) * Cc + hh * 64 + d0;
    float m0 = mlf[ridx], l0 = mlf[ridx + 32768];
    float m1 = mlf[ridx + 65536], l1 = mlf[ridx + 98304];
    float M = fmaxf(m0, m1);
    float a0 = exp2f(m0 - M), a1 = exp2f(m1 - M);
    float inv = 1.f / (l0 * a0 + l1 * a1);
    union { unsigned short u[8]; bf16x8 v; } y0, y1, r;
    y0.v = *(const bf16x8*)(Y + off);
    y1.v = *(const bf16x8*)(P1 + off);
    #pragma unroll
    for (int j = 0; j < 8; ++j)
        r.u[j] = f2bf((bf2f(y0.u[j]) * a0 + bf2f(y1.u[j]) * a1) * inv);
    *(bf16x8*)(Y + off) = r.v;
}

// ---------------------------------------------------------------------------
extern "C" void kernel_launch(void* const* d_in, const int* in_sizes, int n_in,
                              void* d_out, int out_size, void* d_ws, size_t ws_size,
                              hipStream_t stream) {
    const float* x  = (const float*)d_in[0];
    const float* Wq = (const float*)d_in[1];
    const float* Wk = (const float*)d_in[2];
    const float* Wv = (const float*)d_in[3];
    const float* Wo = (const float*)d_in[4];

    unsigned short* ws = (unsigned short*)d_ws;
    const size_t nX = (size_t)Mc * Cc;   // 4194304
    const size_t nW = (size_t)Cc * Cc;   // 1048576
    size_t off = 0;
    unsigned short* xb  = ws + off; off += nX;   // dead after gemm_qkv -> P1
    unsigned short* Wqb = ws + off; off += nW;   // dead after gemm_qkv -> mlf
    unsigned short* Wkb = ws + off; off += nW;
    unsigned short* Wvb = ws + off; off += nW;
    unsigned short* Wob = ws + off; off += nW;
    unsigned short* Qw  = ws + off; off += nX;
    unsigned short* Kw  = ws + off; off += nX;
    unsigned short* Vtw = ws + off; off += nX;
    unsigned short* Yb  = ws + off; off += nX;

    dim3 blk(256);
    cast_bf16<<<dim3((int)(nX / 8 / 256)), blk, 0, stream>>>(x, xb, (int)(nX / 8));
    cast_w4<<<dim3(512, 4), blk, 0, stream>>>(Wq, Wk, Wv, Wo, Wqb, Wkb, Wvb, Wob);

    gemm_qkv<<<dim3(Mc / 128, 48), blk, 0, stream>>>(xb, Wqb, Wkb, Wvb, Qw, Kw, Vtw);

    unsigned short* P1 = xb;
    float* mlf = (float*)Wqb;
    attn_mfma<<<dim3(Bc * Hc, 48), dim3(128), 0, stream>>>(Qw, Kw, Vtw, Yb, P1, mlf);
    attn_combine<<<dim3(1024), blk, 0, stream>>>(Yb, P1, mlf);

    gemm_out<<<dim3(Mc / 64, Cc / 64), blk, 0, stream>>>(Yb, Wob, (float*)d_out);
}

// Round 8
// 128.419 us; speedup vs baseline: 1.0380x; 1.0380x over previous
//
#include <hip/hip_runtime.h>
#include <math.h>

typedef short bf16x8 __attribute__((ext_vector_type(8)));
typedef float f32x4 __attribute__((ext_vector_type(4)));
typedef float f32x16 __attribute__((ext_vector_type(16)));
typedef int int2v __attribute__((ext_vector_type(2)));

constexpr int Bc = 2, Tc = 2048, Cc = 1024, Hc = 16, Dc = 64;
constexpr int Mc = Bc * Tc;  // 4096

#if __has_builtin(__builtin_amdgcn_exp2f)
#define EXP2(x) __builtin_amdgcn_exp2f(x)
#else
#define EXP2(x) exp2f(x)
#endif

#define SBAR() do { asm volatile("" ::: "memory"); \
                    __builtin_amdgcn_s_barrier();   \
                    asm volatile("" ::: "memory"); } while (0)

__device__ __forceinline__ unsigned short f2bf(float f) {
    union { float f; unsigned u; } v; v.f = f;
    unsigned r = v.u + 0x7fffu + ((v.u >> 16) & 1u);  // RNE
    return (unsigned short)(r >> 16);
}

__device__ __forceinline__ float bf2f(unsigned short u) {
    union { unsigned u; float f; } v; v.u = (unsigned)u << 16; return v.f;
}

__device__ __forceinline__ unsigned cvt_pk_bf16(float lo, float hi) {
    unsigned r;
    asm("v_cvt_pk_bf16_f32 %0, %1, %2" : "=v"(r) : "v"(lo), "v"(hi));
    return r;
}

__device__ __forceinline__ void gload16(const void* g, void* l) {
    __builtin_amdgcn_global_load_lds(
        (const __attribute__((address_space(1))) void*)g,
        (__attribute__((address_space(3))) void*)l, 16, 0, 0);
}

// ---------------------------------------------------------------------------
__global__ __launch_bounds__(256)
void cast_bf16(const float* __restrict__ in, unsigned short* __restrict__ out, int n8) {
    int i = blockIdx.x * 256 + threadIdx.x;
    if (i >= n8) return;
    const float4* p = (const float4*)in;
    float4 a = p[i * 2], b = p[i * 2 + 1];
    union { unsigned short u[8]; bf16x8 v; } r;
    r.u[0] = f2bf(a.x); r.u[1] = f2bf(a.y); r.u[2] = f2bf(a.z); r.u[3] = f2bf(a.w);
    r.u[4] = f2bf(b.x); r.u[5] = f2bf(b.y); r.u[6] = f2bf(b.z); r.u[7] = f2bf(b.w);
    *(bf16x8*)(out + i * 8) = r.v;
}

__global__ __launch_bounds__(256)
void cast_w4(const float* __restrict__ a, const float* __restrict__ b,
             const float* __restrict__ c, const float* __restrict__ d,
             unsigned short* __restrict__ oa, unsigned short* __restrict__ ob,
             unsigned short* __restrict__ oc, unsigned short* __restrict__ od) {
    const float* src = blockIdx.y == 0 ? a : blockIdx.y == 1 ? b : blockIdx.y == 2 ? c : d;
    unsigned short* dst = blockIdx.y == 0 ? oa : blockIdx.y == 1 ? ob : blockIdx.y == 2 ? oc : od;
    int i = blockIdx.x * 256 + threadIdx.x;
    const float4* p = (const float4*)src;
    float4 x = p[i * 2], y = p[i * 2 + 1];
    union { unsigned short u[8]; bf16x8 v; } r;
    r.u[0] = f2bf(x.x); r.u[1] = f2bf(x.y); r.u[2] = f2bf(x.z); r.u[3] = f2bf(x.w);
    r.u[4] = f2bf(y.x); r.u[5] = f2bf(y.y); r.u[6] = f2bf(y.z); r.u[7] = f2bf(y.w);
    *(bf16x8*)(dst + i * 8) = r.v;
}

// ---------------------------------------------------------------------------
// Fused QKV GEMM (NT): 128x128 tile, BK=64 (16 K-steps, halved barrier
// drains), 4 waves, 768 blocks. LDS tiles XOR-swizzled (T2, rule 21):
// pre-swizzled global source + swizzled ds_read -> conflict-free b128 reads.
// blockIdx.y: 0..7 -> Q (scaled 0.125*log2e), 8..15 -> K, 16..23 -> V^T.
// ---------------------------------------------------------------------------
__global__ __launch_bounds__(256)
void gemm_qkv(const unsigned short* __restrict__ A,
              const unsigned short* __restrict__ Wq,
              const unsigned short* __restrict__ Wk,
              const unsigned short* __restrict__ Wv,
              unsigned short* __restrict__ Qo,
              unsigned short* __restrict__ Ko,
              unsigned short* __restrict__ Vo) {
    __shared__ unsigned short As[128 * 64];   // 16 KB, swizzled rows of 128B
    __shared__ unsigned short Bs[128 * 64];   // 16 KB
    const int t = threadIdx.x;
    const int lane = t & 63, l15 = lane & 15, l4 = lane >> 4;
    const int w = t >> 6, wr = w >> 1, wc = w & 1;
    const int seg = blockIdx.y >> 3;              // 0=Q 1=K 2=V
    const unsigned short* W = seg == 0 ? Wq : seg == 1 ? Wk : Wv;
    const int m0 = blockIdx.x * 128, n0 = (blockIdx.y & 7) * 128;

    f32x4 acc[4][4] = {};

    for (int k0 = 0; k0 < Cc; k0 += 64) {
        __syncthreads();
        // stage: row = 128B = 8 chunks of 16B; chunk slot XOR'd with row&7 at
        // the SOURCE so a swizzled read returns linear data (involution).
        #pragma unroll
        for (int it = 0; it < 4; ++it) {
            int c = t + it * 256;
            int row = c >> 3, slot = c & 7;
            int ss = slot ^ (row & 7);
            gload16(A + (size_t)(m0 + row) * Cc + k0 + ss * 8, As + c * 8);
            gload16(W + (size_t)(n0 + row) * Cc + k0 + ss * 8, Bs + c * 8);
        }
        __syncthreads();
        #pragma unroll
        for (int kc = 0; kc < 2; ++kc) {
            bf16x8 af[4], bfr[4];
            #pragma unroll
            for (int i = 0; i < 4; ++i) {
                int row = wr * 64 + i * 16 + l15;
                int boff = (kc * 64 + l4 * 16) ^ ((row & 7) << 4);
                af[i] = *(const bf16x8*)(As + row * 64 + (boff >> 1));
            }
            #pragma unroll
            for (int j = 0; j < 4; ++j) {
                int row = wc * 64 + j * 16 + l15;
                int boff = (kc * 64 + l4 * 16) ^ ((row & 7) << 4);
                bfr[j] = *(const bf16x8*)(Bs + row * 64 + (boff >> 1));
            }
            #pragma unroll
            for (int i = 0; i < 4; ++i)
                #pragma unroll
                for (int j = 0; j < 4; ++j)
                    acc[i][j] = __builtin_amdgcn_mfma_f32_16x16x32_bf16(af[i], bfr[j], acc[i][j], 0, 0, 0);
        }
    }

    const float qscale = 0.18033688011112042f;  // 0.125 * log2(e)
    const int r0 = wr * 64 + (l4 << 2);
    const int c0 = wc * 64 + l15;
    #pragma unroll
    for (int i = 0; i < 4; ++i)
        #pragma unroll
        for (int j = 0; j < 4; ++j)
            #pragma unroll
            for (int r = 0; r < 4; ++r) {
                int row = m0 + r0 + i * 16 + r;
                int col = n0 + c0 + j * 16;
                float v = acc[i][j][r];
                int bb = row >> 11, tt = row & (Tc - 1);
                int hh = col >> 6, dd = col & 63;
                if (seg == 0)
                    Qo[((((size_t)bb * Hc + hh) * Tc + tt) << 6) + dd] = f2bf(v * qscale);
                else if (seg == 1)
                    Ko[((((size_t)bb * Hc + hh) * Tc + tt) << 6) + dd] = f2bf(v);
                else
                    Vo[(((size_t)bb * Hc + hh) * Dc + dd) * Tc + tt] = f2bf(v);
            }
}

// ---------------------------------------------------------------------------
// Out-projection GEMM (NT): 64x64 tile, 1024 blocks (4/CU), fp32 out [M,C].
// ---------------------------------------------------------------------------
__global__ __launch_bounds__(256)
void gemm_out(const unsigned short* __restrict__ A,
              const unsigned short* __restrict__ W,
              float* __restrict__ outp) {
    __shared__ unsigned short As[64 * 32];
    __shared__ unsigned short Bs[64 * 32];
    const int t = threadIdx.x;
    const int lane = t & 63, l15 = lane & 15, l4 = lane >> 4;
    const int w = t >> 6, wr = w >> 1, wc = w & 1;
    const int m0 = blockIdx.x * 64, n0 = blockIdx.y * 64;

    f32x4 acc[2][2] = {};

    for (int k0 = 0; k0 < Cc; k0 += 32) {
        __syncthreads();
        {
            int row = t >> 2, ko = (t & 3) << 3;
            gload16(A + (size_t)(m0 + row) * Cc + k0 + ko, As + t * 8);
            gload16(W + (size_t)(n0 + row) * Cc + k0 + ko, Bs + t * 8);
        }
        __syncthreads();
        bf16x8 af[2], bfr[2];
        #pragma unroll
        for (int i = 0; i < 2; ++i)
            af[i] = *(const bf16x8*)(As + ((wr * 32 + i * 16 + l15) * 32 + l4 * 8));
        #pragma unroll
        for (int j = 0; j < 2; ++j)
            bfr[j] = *(const bf16x8*)(Bs + ((wc * 32 + j * 16 + l15) * 32 + l4 * 8));
        #pragma unroll
        for (int i = 0; i < 2; ++i)
            #pragma unroll
            for (int j = 0; j < 2; ++j)
                acc[i][j] = __builtin_amdgcn_mfma_f32_16x16x32_bf16(af[i], bfr[j], acc[i][j], 0, 0, 0);
    }

    const int r0 = wr * 32 + (l4 << 2);
    const int c0 = wc * 32 + l15;
    #pragma unroll
    for (int i = 0; i < 2; ++i)
        #pragma unroll
        for (int j = 0; j < 2; ++j)
            #pragma unroll
            for (int r = 0; r < 4; ++r)
                outp[(size_t)(m0 + r0 + i * 16 + r) * Cc + n0 + c0 + j * 16] = acc[i][j][r];
}

// ---------------------------------------------------------------------------
// MFMA causal flash attention, split-K, counted-vmcnt double-buffer pipeline.
// 64 q-rows per block (2 waves x 32). Job: bit7=split, bit6=half, bits4..0=c.
// ---------------------------------------------------------------------------
__device__ __constant__ unsigned char JOBS[48] = {
    159, 223, 222, 15, 158, 157, 221, 220, 14, 156,
    155, 219, 218, 13, 154, 153, 217, 216, 12, 152,
    151, 215, 214, 11, 150, 149, 213, 212, 10, 148,
    147, 211, 210,  9, 146, 145, 209, 208,  8, 144,
      7,   6,   5,  4,   3,   2,   1,   0
};

__global__ __launch_bounds__(128)
void attn_mfma(const unsigned short* __restrict__ Q,
               const unsigned short* __restrict__ K,
               const unsigned short* __restrict__ Vt,
               unsigned short* __restrict__ Y,
               unsigned short* __restrict__ P1,   // half1 partial O
               float* __restrict__ mlf) {         // m0[32768], l0, m1, l1
    __shared__ unsigned short Ks[2][64 * 64];  // [buf][key][d]   (swizzled)
    __shared__ unsigned short Vs[2][64 * 64];  // [buf][d][key]   (swizzled)

    const int t = threadIdx.x, lane = t & 63, w = t >> 6;
    const int l31 = lane & 31, h = lane >> 5;
    const int bh = blockIdx.x;
    const int bb = bh >> 4, hh = bh & 15;

    const unsigned char job = JOBS[blockIdx.y];
    const int c = job & 31;
    const bool split = job & 128;
    const int half = (job >> 6) & 1;
    const int ntile = c + 1, smid = ntile >> 1;
    const int kb0 = (split && half) ? smid : 0;
    const int kb1 = (split && !half) ? smid : ntile;

    const int qbase = c * 64 + w * 32;
    const int q = qbase + l31;

    const unsigned short* Qp = Q + (size_t)bh * Tc * Dc;
    const unsigned short* Kp = K + (size_t)bh * Tc * Dc;
    const unsigned short* Vp = Vt + (size_t)bh * Dc * Tc;

    // Q as B-operand: col=q=lane&31, k = kc*16 + h*8 + j  (pre-scaled by 0.125*log2e)
    bf16x8 qf[4];
    #pragma unroll
    for (int kc = 0; kc < 4; ++kc)
        qf[kc] = *(const bf16x8*)(Qp + (size_t)q * 64 + kc * 16 + h * 8);

    f32x16 ot[2] = {};          // O^T: rows d=dt*32+(r&3)+8*(r>>2)+4h, col q
    float m = -INFINITY, lsum = 0.f;

    auto stage = [&](int kb, int buf) {
        #pragma unroll
        for (int it = 0; it < 4; ++it) {
            int idx = t + it * 128;
            int row = idx >> 3, slot = idx & 7;
            int ss = slot ^ (row & 7);  // pre-swizzled source
            gload16(Kp + (size_t)(kb * 64 + row) * 64 + ss * 8, &Ks[buf][idx * 8]);
            gload16(Vp + (size_t)row * Tc + kb * 64 + ss * 8, &Vs[buf][idx * 8]);
        }
    };

    stage(kb0, 0);
    if (kb0 + 1 < kb1) stage(kb0 + 1, 1);

    for (int kb = kb0; kb < kb1; ++kb) {
        const int cur = (kb - kb0) & 1;
        // counted wait: stage(kb) complete, stage(kb+1)'s 8 loads stay in flight
        if (kb + 1 < kb1) asm volatile("s_waitcnt vmcnt(8)" ::: "memory");
        else              asm volatile("s_waitcnt vmcnt(0)" ::: "memory");
        SBAR();

        // ---- S^T = K @ Q^T  (log2 domain; 2 key-tiles of 32) ----
        f32x16 st[2] = {};
        __builtin_amdgcn_s_setprio(1);
        #pragma unroll
        for (int nt = 0; nt < 2; ++nt) {
            int key = nt * 32 + l31;
            #pragma unroll
            for (int kc = 0; kc < 4; ++kc) {
                int boff = (kc * 32 + h * 16) ^ ((key & 7) << 4);
                bf16x8 kf = *(const bf16x8*)(&Ks[cur][((key << 7) + boff) >> 1]);
                st[nt] = __builtin_amdgcn_mfma_f32_32x32x16_bf16(kf, qf[kc], st[nt], 0, 0, 0);
            }
        }
        __builtin_amdgcn_s_setprio(0);

        if (kb * 64 + 63 > qbase) {  // causal mask (diagonal tile only)
            #pragma unroll
            for (int nt = 0; nt < 2; ++nt)
                #pragma unroll
                for (int r = 0; r < 16; ++r) {
                    int key = kb * 64 + nt * 32 + (r & 3) + 8 * (r >> 2) + 4 * h;
                    if (key > q) st[nt][r] = -1e30f;
                }
        }

        // ---- lane-local row max ----
        float mx[16];
        #pragma unroll
        for (int r = 0; r < 16; ++r) mx[r] = fmaxf(st[0][r], st[1][r]);
        #pragma unroll
        for (int s2 = 8; s2 > 0; s2 >>= 1)
            #pragma unroll
            for (int r = 0; r < s2; ++r) mx[r] = fmaxf(mx[r], mx[r + s2]);
        float tmax = fmaxf(mx[0], __shfl_xor(mx[0], 32));

        // ---- defer-max (T13) ----
        if (__any(tmax > m + 8.f)) {
            float mn = fmaxf(m, tmax);
            float al = EXP2(m - mn);
            m = mn;
            lsum *= al;
            #pragma unroll
            for (int dt = 0; dt < 2; ++dt)
                #pragma unroll
                for (int r = 0; r < 16; ++r) ot[dt][r] *= al;
        }

        float psa[4] = {0.f, 0.f, 0.f, 0.f};
        #pragma unroll
        for (int nt = 0; nt < 2; ++nt)
            #pragma unroll
            for (int r = 0; r < 16; ++r) {
                float p = EXP2(st[nt][r] - m);
                st[nt][r] = p;
                psa[r & 3] += p;
            }
        lsum += (psa[0] + psa[1]) + (psa[2] + psa[3]);

        // ---- P^T -> bf16 B-frags in-register (T12), then PV ----
        #pragma unroll
        for (int nt = 0; nt < 2; ++nt) {
            unsigned a0 = cvt_pk_bf16(st[nt][0],  st[nt][1]);
            unsigned b0 = cvt_pk_bf16(st[nt][4],  st[nt][5]);
            unsigned a1 = cvt_pk_bf16(st[nt][2],  st[nt][3]);
            unsigned b1 = cvt_pk_bf16(st[nt][6],  st[nt][7]);
            int2v r0 = __builtin_amdgcn_permlane32_swap((int)a0, (int)b0, false, false);
            int2v r1 = __builtin_amdgcn_permlane32_swap((int)a1, (int)b1, false, false);
            union { unsigned u[4]; bf16x8 v; } pf0, pf1;
            pf0.u[0] = r0.x; pf0.u[1] = r1.x; pf0.u[2] = r0.y; pf0.u[3] = r1.y;
            unsigned c0 = cvt_pk_bf16(st[nt][8],  st[nt][9]);
            unsigned d0 = cvt_pk_bf16(st[nt][12], st[nt][13]);
            unsigned c1 = cvt_pk_bf16(st[nt][10], st[nt][11]);
            unsigned d1 = cvt_pk_bf16(st[nt][14], st[nt][15]);
            int2v r2 = __builtin_amdgcn_permlane32_swap((int)c0, (int)d0, false, false);
            int2v r3 = __builtin_amdgcn_permlane32_swap((int)c1, (int)d1, false, false);
            pf1.u[0] = r2.x; pf1.u[1] = r3.x; pf1.u[2] = r2.y; pf1.u[3] = r3.y;

            __builtin_amdgcn_s_setprio(1);
            #pragma unroll
            for (int dt = 0; dt < 2; ++dt) {
                int d = dt * 32 + l31;
                int v0off = (nt * 64 + h * 16) ^ ((d & 7) << 4);
                bf16x8 vf0 = *(const bf16x8*)(&Vs[cur][((d << 7) + v0off) >> 1]);
                ot[dt] = __builtin_amdgcn_mfma_f32_32x32x16_bf16(vf0, pf0.v, ot[dt], 0, 0, 0);
            }
            #pragma unroll
            for (int dt = 0; dt < 2; ++dt) {
                int d = dt * 32 + l31;
                int v1off = (nt * 64 + 32 + h * 16) ^ ((d & 7) << 4);
                bf16x8 vf1 = *(const bf16x8*)(&Vs[cur][((d << 7) + v1off) >> 1]);
                ot[dt] = __builtin_amdgcn_mfma_f32_32x32x16_bf16(vf1, pf1.v, ot[dt], 0, 0, 0);
            }
            __builtin_amdgcn_s_setprio(0);
        }

        SBAR();                     // all waves done reading buf cur
        if (kb + 2 < kb1) stage(kb + 2, cur);
    }

    // ---- epilogue ----
    float lf = lsum + __shfl_xor(lsum, 32);
    unsigned short* dst = (split && half) ? P1 : Y;
    float inv = split ? 1.f : 1.f / lf;
    size_t base = ((size_t)bb * Tc + q) * Cc + hh * 64;
    #pragma unroll
    for (int dt = 0; dt < 2; ++dt)
        #pragma unroll
        for (int rg = 0; rg < 4; ++rg) {
            int d0 = dt * 32 + rg * 8 + 4 * h;
            ushort4 s4;
            s4.x = f2bf(ot[dt][rg * 4 + 0] * inv);
            s4.y = f2bf(ot[dt][rg * 4 + 1] * inv);
            s4.z = f2bf(ot[dt][rg * 4 + 2] * inv);
            s4.w = f2bf(ot[dt][rg * 4 + 3] * inv);
            *(ushort4*)(dst + base + d0) = s4;
        }
    if (split && h == 0) {
        int ridx = bh * 1024 + (q - 1024);
        mlf[ridx + (half ? 65536 : 0)]     = m;   // m
        mlf[ridx + (half ? 98304 : 32768)] = lf;  // l
    }
}

// ---------------------------------------------------------------------------
__global__ __launch_bounds__(256)
void attn_combine(unsigned short* __restrict__ Y,
                  const unsigned short* __restrict__ P1,
                  const float* __restrict__ mlf) {
    int tid = blockIdx.x * 256 + threadIdx.x;   // 0 .. 262143
    int ridx = tid >> 3;
    int d0 = (tid & 7) * 8;
    int bh = ridx >> 10, qq = ridx & 1023;
    int bb = bh >> 4, hh = bh & 15;
    int q = 1024 + qq;
    size_t off = ((size_t)bb * Tc + q) * Cc + hh * 64 + d0;
    float m0 = mlf[ridx], l0 = mlf[ridx + 32768];
    float m1 = mlf[ridx + 65536], l1 = mlf[ridx + 98304];
    float M = fmaxf(m0, m1);
    float a0 = exp2f(m0 - M), a1 = exp2f(m1 - M);
    float inv = 1.f / (l0 * a0 + l1 * a1);
    union { unsigned short u[8]; bf16x8 v; } y0, y1, r;
    y0.v = *(const bf16x8*)(Y + off);
    y1.v = *(const bf16x8*)(P1 + off);
    #pragma unroll
    for (int j = 0; j < 8; ++j)
        r.u[j] = f2bf((bf2f(y0.u[j]) * a0 + bf2f(y1.u[j]) * a1) * inv);
    *(bf16x8*)(Y + off) = r.v;
}

// ---------------------------------------------------------------------------
extern "C" void kernel_launch(void* const* d_in, const int* in_sizes, int n_in,
                              void* d_out, int out_size, void* d_ws, size_t ws_size,
                              hipStream_t stream) {
    const float* x  = (const float*)d_in[0];
    const float* Wq = (const float*)d_in[1];
    const float* Wk = (const float*)d_in[2];
    const float* Wv = (const float*)d_in[3];
    const float* Wo = (const float*)d_in[4];

    unsigned short* ws = (unsigned short*)d_ws;
    const size_t nX = (size_t)Mc * Cc;   // 4194304
    const size_t nW = (size_t)Cc * Cc;   // 1048576
    size_t off = 0;
    unsigned short* xb  = ws + off; off += nX;   // dead after gemm_qkv -> P1
    unsigned short* Wqb = ws + off; off += nW;   // dead after gemm_qkv -> mlf
    unsigned short* Wkb = ws + off; off += nW;
    unsigned short* Wvb = ws + off; off += nW;
    unsigned short* Wob = ws + off; off += nW;
    unsigned short* Qw  = ws + off; off += nX;
    unsigned short* Kw  = ws + off; off += nX;
    unsigned short* Vtw = ws + off; off += nX;
    unsigned short* Yb  = ws + off; off += nX;

    dim3 blk(256);
    cast_bf16<<<dim3((int)(nX / 8 / 256)), blk, 0, stream>>>(x, xb, (int)(nX / 8));
    cast_w4<<<dim3(512, 4), blk, 0, stream>>>(Wq, Wk, Wv, Wo, Wqb, Wkb, Wvb, Wob);

    gemm_qkv<<<dim3(Mc / 128, 24), blk, 0, stream>>>(xb, Wqb, Wkb, Wvb, Qw, Kw, Vtw);

    unsigned short* P1 = xb;
    float* mlf = (float*)Wqb;
    attn_mfma<<<dim3(Bc * Hc, 48), dim3(128), 0, stream>>>(Qw, Kw, Vtw, Yb, P1, mlf);
    attn_combine<<<dim3(1024), blk, 0, stream>>>(Yb, P1, mlf);

    gemm_out<<<dim3(Mc / 64, Cc / 64), blk, 0, stream>>>(Yb, Wob, (float*)d_out);
}

// Round 9
// 123.159 us; speedup vs baseline: 1.0823x; 1.0427x over previous
//
#include <hip/hip_runtime.h>
#include <math.h>

typedef short bf16x8 __attribute__((ext_vector_type(8)));
typedef float f32x4 __attribute__((ext_vector_type(4)));
typedef float f32x16 __attribute__((ext_vector_type(16)));
typedef int int2v __attribute__((ext_vector_type(2)));

constexpr int Bc = 2, Tc = 2048, Cc = 1024, Hc = 16, Dc = 64;
constexpr int Mc = Bc * Tc;  // 4096

#if __has_builtin(__builtin_amdgcn_exp2f)
#define EXP2(x) __builtin_amdgcn_exp2f(x)
#else
#define EXP2(x) exp2f(x)
#endif

#define SBAR() do { asm volatile("" ::: "memory"); \
                    __builtin_amdgcn_s_barrier();   \
                    asm volatile("" ::: "memory"); } while (0)

__device__ __forceinline__ unsigned short f2bf(float f) {
    union { float f; unsigned u; } v; v.f = f;
    unsigned r = v.u + 0x7fffu + ((v.u >> 16) & 1u);  // RNE
    return (unsigned short)(r >> 16);
}

__device__ __forceinline__ float bf2f(unsigned short u) {
    union { unsigned u; float f; } v; v.u = (unsigned)u << 16; return v.f;
}

__device__ __forceinline__ unsigned cvt_pk_bf16(float lo, float hi) {
    unsigned r;
    asm("v_cvt_pk_bf16_f32 %0, %1, %2" : "=v"(r) : "v"(lo), "v"(hi));
    return r;
}

__device__ __forceinline__ void gload16(const void* g, void* l) {
    __builtin_amdgcn_global_load_lds(
        (const __attribute__((address_space(1))) void*)g,
        (__attribute__((address_space(3))) void*)l, 16, 0, 0);
}

// ---------------------------------------------------------------------------
__global__ __launch_bounds__(256)
void cast_bf16(const float* __restrict__ in, unsigned short* __restrict__ out, int n8) {
    int i = blockIdx.x * 256 + threadIdx.x;
    if (i >= n8) return;
    const float4* p = (const float4*)in;
    float4 a = p[i * 2], b = p[i * 2 + 1];
    union { unsigned short u[8]; bf16x8 v; } r;
    r.u[0] = f2bf(a.x); r.u[1] = f2bf(a.y); r.u[2] = f2bf(a.z); r.u[3] = f2bf(a.w);
    r.u[4] = f2bf(b.x); r.u[5] = f2bf(b.y); r.u[6] = f2bf(b.z); r.u[7] = f2bf(b.w);
    *(bf16x8*)(out + i * 8) = r.v;
}

__global__ __launch_bounds__(256)
void cast_w4(const float* __restrict__ a, const float* __restrict__ b,
             const float* __restrict__ c, const float* __restrict__ d,
             unsigned short* __restrict__ oa, unsigned short* __restrict__ ob,
             unsigned short* __restrict__ oc, unsigned short* __restrict__ od) {
    const float* src = blockIdx.y == 0 ? a : blockIdx.y == 1 ? b : blockIdx.y == 2 ? c : d;
    unsigned short* dst = blockIdx.y == 0 ? oa : blockIdx.y == 1 ? ob : blockIdx.y == 2 ? oc : od;
    int i = blockIdx.x * 256 + threadIdx.x;
    const float4* p = (const float4*)src;
    float4 x = p[i * 2], y = p[i * 2 + 1];
    union { unsigned short u[8]; bf16x8 v; } r;
    r.u[0] = f2bf(x.x); r.u[1] = f2bf(x.y); r.u[2] = f2bf(x.z); r.u[3] = f2bf(x.w);
    r.u[4] = f2bf(y.x); r.u[5] = f2bf(y.y); r.u[6] = f2bf(y.z); r.u[7] = f2bf(y.w);
    *(bf16x8*)(dst + i * 8) = r.v;
}

// ---------------------------------------------------------------------------
// Fused QKV GEMM (NT) -- R4 best-known config restored verbatim:
// 128x128 tile, BK=32, 4 waves, single-buffer 2-barrier loop, 768 blocks.
// blockIdx.y: 0..7 -> Q (scaled 0.125*log2e), 8..15 -> K, 16..23 -> V^T.
// ---------------------------------------------------------------------------
__global__ __launch_bounds__(256)
void gemm_qkv(const unsigned short* __restrict__ A,
              const unsigned short* __restrict__ Wq,
              const unsigned short* __restrict__ Wk,
              const unsigned short* __restrict__ Wv,
              unsigned short* __restrict__ Qo,
              unsigned short* __restrict__ Ko,
              unsigned short* __restrict__ Vo) {
    __shared__ unsigned short As[128 * 32];
    __shared__ unsigned short Bs[128 * 32];
    const int t = threadIdx.x;
    const int lane = t & 63, l15 = lane & 15, l4 = lane >> 4;
    const int w = t >> 6, wr = w >> 1, wc = w & 1;
    const int seg = blockIdx.y >> 3;              // 0=Q 1=K 2=V
    const unsigned short* W = seg == 0 ? Wq : seg == 1 ? Wk : Wv;
    const int m0 = blockIdx.x * 128, n0 = (blockIdx.y & 7) * 128;

    f32x4 acc[4][4] = {};

    for (int k0 = 0; k0 < Cc; k0 += 32) {
        __syncthreads();
        #pragma unroll
        for (int it = 0; it < 2; ++it) {
            int c = t + it * 256;
            int row = c >> 2, ko = (c & 3) << 3;
            gload16(A + (size_t)(m0 + row) * Cc + k0 + ko, As + c * 8);
            gload16(W + (size_t)(n0 + row) * Cc + k0 + ko, Bs + c * 8);
        }
        __syncthreads();
        bf16x8 af[4], bfr[4];
        #pragma unroll
        for (int i = 0; i < 4; ++i)
            af[i] = *(const bf16x8*)(As + ((wr * 64 + i * 16 + l15) * 32 + l4 * 8));
        #pragma unroll
        for (int j = 0; j < 4; ++j)
            bfr[j] = *(const bf16x8*)(Bs + ((wc * 64 + j * 16 + l15) * 32 + l4 * 8));
        #pragma unroll
        for (int i = 0; i < 4; ++i)
            #pragma unroll
            for (int j = 0; j < 4; ++j)
                acc[i][j] = __builtin_amdgcn_mfma_f32_16x16x32_bf16(af[i], bfr[j], acc[i][j], 0, 0, 0);
    }

    const float qscale = 0.18033688011112042f;  // 0.125 * log2(e)
    const int r0 = wr * 64 + (l4 << 2);
    const int c0 = wc * 64 + l15;
    #pragma unroll
    for (int i = 0; i < 4; ++i)
        #pragma unroll
        for (int j = 0; j < 4; ++j)
            #pragma unroll
            for (int r = 0; r < 4; ++r) {
                int row = m0 + r0 + i * 16 + r;
                int col = n0 + c0 + j * 16;
                float v = acc[i][j][r];
                int bb = row >> 11, tt = row & (Tc - 1);
                int hh = col >> 6, dd = col & 63;
                if (seg == 0)
                    Qo[((((size_t)bb * Hc + hh) * Tc + tt) << 6) + dd] = f2bf(v * qscale);
                else if (seg == 1)
                    Ko[((((size_t)bb * Hc + hh) * Tc + tt) << 6) + dd] = f2bf(v);
                else
                    Vo[(((size_t)bb * Hc + hh) * Dc + dd) * Tc + tt] = f2bf(v);
            }
}

// ---------------------------------------------------------------------------
// Out-projection GEMM (NT): 64x64 tile, 1024 blocks (4/CU), fp32 out [M,C].
// ---------------------------------------------------------------------------
__global__ __launch_bounds__(256)
void gemm_out(const unsigned short* __restrict__ A,
              const unsigned short* __restrict__ W,
              float* __restrict__ outp) {
    __shared__ unsigned short As[64 * 32];
    __shared__ unsigned short Bs[64 * 32];
    const int t = threadIdx.x;
    const int lane = t & 63, l15 = lane & 15, l4 = lane >> 4;
    const int w = t >> 6, wr = w >> 1, wc = w & 1;
    const int m0 = blockIdx.x * 64, n0 = blockIdx.y * 64;

    f32x4 acc[2][2] = {};

    for (int k0 = 0; k0 < Cc; k0 += 32) {
        __syncthreads();
        {
            int row = t >> 2, ko = (t & 3) << 3;
            gload16(A + (size_t)(m0 + row) * Cc + k0 + ko, As + t * 8);
            gload16(W + (size_t)(n0 + row) * Cc + k0 + ko, Bs + t * 8);
        }
        __syncthreads();
        bf16x8 af[2], bfr[2];
        #pragma unroll
        for (int i = 0; i < 2; ++i)
            af[i] = *(const bf16x8*)(As + ((wr * 32 + i * 16 + l15) * 32 + l4 * 8));
        #pragma unroll
        for (int j = 0; j < 2; ++j)
            bfr[j] = *(const bf16x8*)(Bs + ((wc * 32 + j * 16 + l15) * 32 + l4 * 8));
        #pragma unroll
        for (int i = 0; i < 2; ++i)
            #pragma unroll
            for (int j = 0; j < 2; ++j)
                acc[i][j] = __builtin_amdgcn_mfma_f32_16x16x32_bf16(af[i], bfr[j], acc[i][j], 0, 0, 0);
    }

    const int r0 = wr * 32 + (l4 << 2);
    const int c0 = wc * 32 + l15;
    #pragma unroll
    for (int i = 0; i < 2; ++i)
        #pragma unroll
        for (int j = 0; j < 2; ++j)
            #pragma unroll
            for (int r = 0; r < 4; ++r)
                outp[(size_t)(m0 + r0 + i * 16 + r) * Cc + n0 + c0 + j * 16] = acc[i][j][r];
}

// ---------------------------------------------------------------------------
// MFMA causal flash attention, split-K. K staged in LDS (dbuf, swizzled,
// counted vmcnt); V^T read DIRECTLY from global into registers (L2-resident:
// all jobs of a head land on one XCD since linear id % 8 == blockIdx.x % 8).
// 64 q-rows per block (2 waves x 32). Job: bit7=split, bit6=half, bits4..0=c.
// ---------------------------------------------------------------------------
__device__ __constant__ unsigned char JOBS[48] = {
    159, 223, 222, 15, 158, 157, 221, 220, 14, 156,
    155, 219, 218, 13, 154, 153, 217, 216, 12, 152,
    151, 215, 214, 11, 150, 149, 213, 212, 10, 148,
    147, 211, 210,  9, 146, 145, 209, 208,  8, 144,
      7,   6,   5,  4,   3,   2,   1,   0
};

__global__ __launch_bounds__(128)
void attn_mfma(const unsigned short* __restrict__ Q,
               const unsigned short* __restrict__ K,
               const unsigned short* __restrict__ Vt,
               unsigned short* __restrict__ Y,
               unsigned short* __restrict__ P1,   // half1 partial O
               float* __restrict__ mlf) {         // m0[32768], l0, m1, l1
    __shared__ unsigned short Ks[2][64 * 64];  // [buf][key][d] swizzled, 16 KB

    const int t = threadIdx.x, lane = t & 63, w = t >> 6;
    const int l31 = lane & 31, h = lane >> 5;
    const int bh = blockIdx.x;
    const int bb = bh >> 4, hh = bh & 15;

    const unsigned char job = JOBS[blockIdx.y];
    const int c = job & 31;
    const bool split = job & 128;
    const int half = (job >> 6) & 1;
    const int ntile = c + 1, smid = ntile >> 1;
    const int kb0 = (split && half) ? smid : 0;
    const int kb1 = (split && !half) ? smid : ntile;

    const int qbase = c * 64 + w * 32;
    const int q = qbase + l31;

    const unsigned short* Qp = Q + (size_t)bh * Tc * Dc;
    const unsigned short* Kp = K + (size_t)bh * Tc * Dc;
    const unsigned short* Vp = Vt + (size_t)bh * Dc * Tc;

    // Q as B-operand: col=q=lane&31, k = kc*16 + h*8 + j  (pre-scaled by 0.125*log2e)
    bf16x8 qf[4];
    #pragma unroll
    for (int kc = 0; kc < 4; ++kc)
        qf[kc] = *(const bf16x8*)(Qp + (size_t)q * 64 + kc * 16 + h * 8);

    f32x16 ot[2] = {};          // O^T: rows d=dt*32+(r&3)+8*(r>>2)+4h, col q
    float m = -INFINITY, lsum = 0.f;

    auto stageK = [&](int kb, int buf) {
        #pragma unroll
        for (int it = 0; it < 4; ++it) {
            int idx = t + it * 128;
            int row = idx >> 3, slot = idx & 7;
            int ss = slot ^ (row & 7);  // pre-swizzled source
            gload16(Kp + (size_t)(kb * 64 + row) * 64 + ss * 8, &Ks[buf][idx * 8]);
        }
    };

    stageK(kb0, 0);
    if (kb0 + 1 < kb1) stageK(kb0 + 1, 1);

    for (int kb = kb0; kb < kb1; ++kb) {
        const int cur = (kb - kb0) & 1;
        // counted wait: stage(kb) complete; stage(kb+1)'s 4 loads stay in flight
        if (kb + 1 < kb1) asm volatile("s_waitcnt vmcnt(4)" ::: "memory");
        else              asm volatile("s_waitcnt vmcnt(0)" ::: "memory");
        SBAR();

        // ---- V^T fragments straight from global (L2-hit ~200cy, hidden
        //      under QK^T + softmax). [nt][ks][dt], A-operand of PV. ----
        bf16x8 vf[2][2][2];
        #pragma unroll
        for (int nt = 0; nt < 2; ++nt)
            #pragma unroll
            for (int ks = 0; ks < 2; ++ks)
                #pragma unroll
                for (int dt = 0; dt < 2; ++dt)
                    vf[nt][ks][dt] = *(const bf16x8*)(
                        Vp + (size_t)(dt * 32 + l31) * Tc
                           + kb * 64 + nt * 32 + ks * 16 + h * 8);

        // ---- S^T = K @ Q^T  (log2 domain; 2 key-tiles of 32) ----
        f32x16 st[2] = {};
        __builtin_amdgcn_s_setprio(1);
        #pragma unroll
        for (int nt = 0; nt < 2; ++nt) {
            int key = nt * 32 + l31;
            #pragma unroll
            for (int kc = 0; kc < 4; ++kc) {
                int boff = (kc * 32 + h * 16) ^ ((key & 7) << 4);
                bf16x8 kf = *(const bf16x8*)(&Ks[cur][((key << 7) + boff) >> 1]);
                st[nt] = __builtin_amdgcn_mfma_f32_32x32x16_bf16(kf, qf[kc], st[nt], 0, 0, 0);
            }
        }
        __builtin_amdgcn_s_setprio(0);

        if (kb * 64 + 63 > qbase) {  // causal mask (diagonal tile only)
            #pragma unroll
            for (int nt = 0; nt < 2; ++nt)
                #pragma unroll
                for (int r = 0; r < 16; ++r) {
                    int key = kb * 64 + nt * 32 + (r & 3) + 8 * (r >> 2) + 4 * h;
                    if (key > q) st[nt][r] = -1e30f;
                }
        }

        // ---- lane-local row max ----
        float mx[16];
        #pragma unroll
        for (int r = 0; r < 16; ++r) mx[r] = fmaxf(st[0][r], st[1][r]);
        #pragma unroll
        for (int s2 = 8; s2 > 0; s2 >>= 1)
            #pragma unroll
            for (int r = 0; r < s2; ++r) mx[r] = fmaxf(mx[r], mx[r + s2]);
        float tmax = fmaxf(mx[0], __shfl_xor(mx[0], 32));

        // ---- defer-max (T13) ----
        if (__any(tmax > m + 8.f)) {
            float mn = fmaxf(m, tmax);
            float al = EXP2(m - mn);
            m = mn;
            lsum *= al;
            #pragma unroll
            for (int dt = 0; dt < 2; ++dt)
                #pragma unroll
                for (int r = 0; r < 16; ++r) ot[dt][r] *= al;
        }

        float psa[4] = {0.f, 0.f, 0.f, 0.f};
        #pragma unroll
        for (int nt = 0; nt < 2; ++nt)
            #pragma unroll
            for (int r = 0; r < 16; ++r) {
                float p = EXP2(st[nt][r] - m);
                st[nt][r] = p;
                psa[r & 3] += p;
            }
        lsum += (psa[0] + psa[1]) + (psa[2] + psa[3]);

        // ---- P^T -> bf16 B-frags in-register (T12), then PV ----
        #pragma unroll
        for (int nt = 0; nt < 2; ++nt) {
            unsigned a0 = cvt_pk_bf16(st[nt][0],  st[nt][1]);
            unsigned b0 = cvt_pk_bf16(st[nt][4],  st[nt][5]);
            unsigned a1 = cvt_pk_bf16(st[nt][2],  st[nt][3]);
            unsigned b1 = cvt_pk_bf16(st[nt][6],  st[nt][7]);
            int2v r0 = __builtin_amdgcn_permlane32_swap((int)a0, (int)b0, false, false);
            int2v r1 = __builtin_amdgcn_permlane32_swap((int)a1, (int)b1, false, false);
            union { unsigned u[4]; bf16x8 v; } pf0, pf1;
            pf0.u[0] = r0.x; pf0.u[1] = r1.x; pf0.u[2] = r0.y; pf0.u[3] = r1.y;
            unsigned c0 = cvt_pk_bf16(st[nt][8],  st[nt][9]);
            unsigned d0 = cvt_pk_bf16(st[nt][12], st[nt][13]);
            unsigned c1 = cvt_pk_bf16(st[nt][10], st[nt][11]);
            unsigned d1 = cvt_pk_bf16(st[nt][14], st[nt][15]);
            int2v r2 = __builtin_amdgcn_permlane32_swap((int)c0, (int)d0, false, false);
            int2v r3 = __builtin_amdgcn_permlane32_swap((int)c1, (int)d1, false, false);
            pf1.u[0] = r2.x; pf1.u[1] = r3.x; pf1.u[2] = r2.y; pf1.u[3] = r3.y;

            __builtin_amdgcn_s_setprio(1);
            #pragma unroll
            for (int dt = 0; dt < 2; ++dt)
                ot[dt] = __builtin_amdgcn_mfma_f32_32x32x16_bf16(vf[nt][0][dt], pf0.v, ot[dt], 0, 0, 0);
            #pragma unroll
            for (int dt = 0; dt < 2; ++dt)
                ot[dt] = __builtin_amdgcn_mfma_f32_32x32x16_bf16(vf[nt][1][dt], pf1.v, ot[dt], 0, 0, 0);
            __builtin_amdgcn_s_setprio(0);
        }

        SBAR();                     // all waves done reading Ks[cur]
        if (kb + 2 < kb1) stageK(kb + 2, cur);
    }

    // ---- epilogue ----
    float lf = lsum + __shfl_xor(lsum, 32);
    unsigned short* dst = (split && half) ? P1 : Y;
    float inv = split ? 1.f : 1.f / lf;
    size_t base = ((size_t)bb * Tc + q) * Cc + hh * 64;
    #pragma unroll
    for (int dt = 0; dt < 2; ++dt)
        #pragma unroll
        for (int rg = 0; rg < 4; ++rg) {
            int d0 = dt * 32 + rg * 8 + 4 * h;
            ushort4 s4;
            s4.x = f2bf(ot[dt][rg * 4 + 0] * inv);
            s4.y = f2bf(ot[dt][rg * 4 + 1] * inv);
            s4.z = f2bf(ot[dt][rg * 4 + 2] * inv);
            s4.w = f2bf(ot[dt][rg * 4 + 3] * inv);
            *(ushort4*)(dst + base + d0) = s4;
        }
    if (split && h == 0) {
        int ridx = bh * 1024 + (q - 1024);
        mlf[ridx + (half ? 65536 : 0)]     = m;   // m
        mlf[ridx + (half ? 98304 : 32768)] = lf;  // l
    }
}

// ---------------------------------------------------------------------------
__global__ __launch_bounds__(256)
void attn_combine(unsigned short* __restrict__ Y,
                  const unsigned short* __restrict__ P1,
                  const float* __restrict__ mlf) {
    int tid = blockIdx.x * 256 + threadIdx.x;   // 0 .. 262143
    int ridx = tid >> 3;
    int d0 = (tid & 7) * 8;
    int bh = ridx >> 10, qq = ridx & 1023;
    int bb = bh >> 4, hh = bh & 15;
    int q = 1024 + qq;
    size_t off = ((size_t)bb * Tc + q) * Cc + hh * 64 + d0;
    float m0 = mlf[ridx], l0 = mlf[ridx + 32768];
    float m1 = mlf[ridx + 65536], l1 = mlf[ridx + 98304];
    float M = fmaxf(m0, m1);
    float a0 = exp2f(m0 - M), a1 = exp2f(m1 - M);
    float inv = 1.f / (l0 * a0 + l1 * a1);
    union { unsigned short u[8]; bf16x8 v; } y0, y1, r;
    y0.v = *(const bf16x8*)(Y + off);
    y1.v = *(const bf16x8*)(P1 + off);
    #pragma unroll
    for (int j = 0; j < 8; ++j)
        r.u[j] = f2bf((bf2f(y0.u[j]) * a0 + bf2f(y1.u[j]) * a1) * inv);
    *(bf16x8*)(Y + off) = r.v;
}

// ---------------------------------------------------------------------------
extern "C" void kernel_launch(void* const* d_in, const int* in_sizes, int n_in,
                              void* d_out, int out_size, void* d_ws, size_t ws_size,
                              hipStream_t stream) {
    const float* x  = (const float*)d_in[0];
    const float* Wq = (const float*)d_in[1];
    const float* Wk = (const float*)d_in[2];
    const float* Wv = (const float*)d_in[3];
    const float* Wo = (const float*)d_in[4];

    unsigned short* ws = (unsigned short*)d_ws;
    const size_t nX = (size_t)Mc * Cc;   // 4194304
    const size_t nW = (size_t)Cc * Cc;   // 1048576
    size_t off = 0;
    unsigned short* xb  = ws + off; off += nX;   // dead after gemm_qkv -> P1
    unsigned short* Wqb = ws + off; off += nW;   // dead after gemm_qkv -> mlf
    unsigned short* Wkb = ws + off; off += nW;
    unsigned short* Wvb = ws + off; off += nW;
    unsigned short* Wob = ws + off; off += nW;
    unsigned short* Qw  = ws + off; off += nX;
    unsigned short* Kw  = ws + off; off += nX;
    unsigned short* Vtw = ws + off; off += nX;
    unsigned short* Yb  = ws + off; off += nX;

    dim3 blk(256);
    cast_bf16<<<dim3((int)(nX / 8 / 256)), blk, 0, stream>>>(x, xb, (int)(nX / 8));
    cast_w4<<<dim3(512, 4), blk, 0, stream>>>(Wq, Wk, Wv, Wo, Wqb, Wkb, Wvb, Wob);

    gemm_qkv<<<dim3(Mc / 128, 24), blk, 0, stream>>>(xb, Wqb, Wkb, Wvb, Qw, Kw, Vtw);

    unsigned short* P1 = xb;
    float* mlf = (float*)Wqb;
    attn_mfma<<<dim3(Bc * Hc, 48), dim3(128), 0, stream>>>(Qw, Kw, Vtw, Yb, P1, mlf);
    attn_combine<<<dim3(1024), blk, 0, stream>>>(Yb, P1, mlf);

    gemm_out<<<dim3(Mc / 64, Cc / 64), blk, 0, stream>>>(Yb, Wob, (float*)d_out);
}

// Round 10
// 119.127 us; speedup vs baseline: 1.1189x; 1.0338x over previous
//
#include <hip/hip_runtime.h>
#include <math.h>

typedef short bf16x8 __attribute__((ext_vector_type(8)));
typedef float f32x4 __attribute__((ext_vector_type(4)));
typedef float f32x16 __attribute__((ext_vector_type(16)));
typedef int int2v __attribute__((ext_vector_type(2)));

constexpr int Bc = 2, Tc = 2048, Cc = 1024, Hc = 16, Dc = 64;
constexpr int Mc = Bc * Tc;  // 4096

#if __has_builtin(__builtin_amdgcn_exp2f)
#define EXP2(x) __builtin_amdgcn_exp2f(x)
#else
#define EXP2(x) exp2f(x)
#endif

#define SBAR() do { asm volatile("" ::: "memory"); \
                    __builtin_amdgcn_s_barrier();   \
                    asm volatile("" ::: "memory"); } while (0)

__device__ __forceinline__ unsigned short f2bf(float f) {
    union { float f; unsigned u; } v; v.f = f;
    unsigned r = v.u + 0x7fffu + ((v.u >> 16) & 1u);  // RNE
    return (unsigned short)(r >> 16);
}

__device__ __forceinline__ float bf2f(unsigned short u) {
    union { unsigned u; float f; } v; v.u = (unsigned)u << 16; return v.f;
}

__device__ __forceinline__ unsigned cvt_pk_bf16(float lo, float hi) {
    unsigned r;
    asm("v_cvt_pk_bf16_f32 %0, %1, %2" : "=v"(r) : "v"(lo), "v"(hi));
    return r;
}

__device__ __forceinline__ void gload16(const void* g, void* l) {
    __builtin_amdgcn_global_load_lds(
        (const __attribute__((address_space(1))) void*)g,
        (__attribute__((address_space(3))) void*)l, 16, 0, 0);
}

// ---------------------------------------------------------------------------
__global__ __launch_bounds__(256)
void cast_bf16(const float* __restrict__ in, unsigned short* __restrict__ out, int n8) {
    int i = blockIdx.x * 256 + threadIdx.x;
    if (i >= n8) return;
    const float4* p = (const float4*)in;
    float4 a = p[i * 2], b = p[i * 2 + 1];
    union { unsigned short u[8]; bf16x8 v; } r;
    r.u[0] = f2bf(a.x); r.u[1] = f2bf(a.y); r.u[2] = f2bf(a.z); r.u[3] = f2bf(a.w);
    r.u[4] = f2bf(b.x); r.u[5] = f2bf(b.y); r.u[6] = f2bf(b.z); r.u[7] = f2bf(b.w);
    *(bf16x8*)(out + i * 8) = r.v;
}

__global__ __launch_bounds__(256)
void cast_w4(const float* __restrict__ a, const float* __restrict__ b,
             const float* __restrict__ c, const float* __restrict__ d,
             unsigned short* __restrict__ oa, unsigned short* __restrict__ ob,
             unsigned short* __restrict__ oc, unsigned short* __restrict__ od) {
    const float* src = blockIdx.y == 0 ? a : blockIdx.y == 1 ? b : blockIdx.y == 2 ? c : d;
    unsigned short* dst = blockIdx.y == 0 ? oa : blockIdx.y == 1 ? ob : blockIdx.y == 2 ? oc : od;
    int i = blockIdx.x * 256 + threadIdx.x;
    const float4* p = (const float4*)src;
    float4 x = p[i * 2], y = p[i * 2 + 1];
    union { unsigned short u[8]; bf16x8 v; } r;
    r.u[0] = f2bf(x.x); r.u[1] = f2bf(x.y); r.u[2] = f2bf(x.z); r.u[3] = f2bf(x.w);
    r.u[4] = f2bf(y.x); r.u[5] = f2bf(y.y); r.u[6] = f2bf(y.z); r.u[7] = f2bf(y.w);
    *(bf16x8*)(dst + i * 8) = r.v;
}

// ---------------------------------------------------------------------------
// Fused QKV GEMM (NT) -- best-known config (R4): 128x128 tile, BK=32,
// 4 waves, single-buffer 2-barrier loop, 768 blocks.
// blockIdx.y: 0..7 -> Q (scaled 0.125*log2e), 8..15 -> K, 16..23 -> V^T.
// ---------------------------------------------------------------------------
__global__ __launch_bounds__(256)
void gemm_qkv(const unsigned short* __restrict__ A,
              const unsigned short* __restrict__ Wq,
              const unsigned short* __restrict__ Wk,
              const unsigned short* __restrict__ Wv,
              unsigned short* __restrict__ Qo,
              unsigned short* __restrict__ Ko,
              unsigned short* __restrict__ Vo) {
    __shared__ unsigned short As[128 * 32];
    __shared__ unsigned short Bs[128 * 32];
    const int t = threadIdx.x;
    const int lane = t & 63, l15 = lane & 15, l4 = lane >> 4;
    const int w = t >> 6, wr = w >> 1, wc = w & 1;
    const int seg = blockIdx.y >> 3;              // 0=Q 1=K 2=V
    const unsigned short* W = seg == 0 ? Wq : seg == 1 ? Wk : Wv;
    const int m0 = blockIdx.x * 128, n0 = (blockIdx.y & 7) * 128;

    f32x4 acc[4][4] = {};

    for (int k0 = 0; k0 < Cc; k0 += 32) {
        __syncthreads();
        #pragma unroll
        for (int it = 0; it < 2; ++it) {
            int c = t + it * 256;
            int row = c >> 2, ko = (c & 3) << 3;
            gload16(A + (size_t)(m0 + row) * Cc + k0 + ko, As + c * 8);
            gload16(W + (size_t)(n0 + row) * Cc + k0 + ko, Bs + c * 8);
        }
        __syncthreads();
        bf16x8 af[4], bfr[4];
        #pragma unroll
        for (int i = 0; i < 4; ++i)
            af[i] = *(const bf16x8*)(As + ((wr * 64 + i * 16 + l15) * 32 + l4 * 8));
        #pragma unroll
        for (int j = 0; j < 4; ++j)
            bfr[j] = *(const bf16x8*)(Bs + ((wc * 64 + j * 16 + l15) * 32 + l4 * 8));
        #pragma unroll
        for (int i = 0; i < 4; ++i)
            #pragma unroll
            for (int j = 0; j < 4; ++j)
                acc[i][j] = __builtin_amdgcn_mfma_f32_16x16x32_bf16(af[i], bfr[j], acc[i][j], 0, 0, 0);
    }

    const float qscale = 0.18033688011112042f;  // 0.125 * log2(e)
    const int r0 = wr * 64 + (l4 << 2);
    const int c0 = wc * 64 + l15;
    #pragma unroll
    for (int i = 0; i < 4; ++i)
        #pragma unroll
        for (int j = 0; j < 4; ++j)
            #pragma unroll
            for (int r = 0; r < 4; ++r) {
                int row = m0 + r0 + i * 16 + r;
                int col = n0 + c0 + j * 16;
                float v = acc[i][j][r];
                int bb = row >> 11, tt = row & (Tc - 1);
                int hh = col >> 6, dd = col & 63;
                if (seg == 0)
                    Qo[((((size_t)bb * Hc + hh) * Tc + tt) << 6) + dd] = f2bf(v * qscale);
                else if (seg == 1)
                    Ko[((((size_t)bb * Hc + hh) * Tc + tt) << 6) + dd] = f2bf(v);
                else
                    Vo[(((size_t)bb * Hc + hh) * Dc + dd) * Tc + tt] = f2bf(v);
            }
}

// ---------------------------------------------------------------------------
// Out-projection GEMM (NT): 64x64 tile, 1024 blocks (4/CU), fp32 out [M,C].
// ---------------------------------------------------------------------------
__global__ __launch_bounds__(256)
void gemm_out(const unsigned short* __restrict__ A,
              const unsigned short* __restrict__ W,
              float* __restrict__ outp) {
    __shared__ unsigned short As[64 * 32];
    __shared__ unsigned short Bs[64 * 32];
    const int t = threadIdx.x;
    const int lane = t & 63, l15 = lane & 15, l4 = lane >> 4;
    const int w = t >> 6, wr = w >> 1, wc = w & 1;
    const int m0 = blockIdx.x * 64, n0 = blockIdx.y * 64;

    f32x4 acc[2][2] = {};

    for (int k0 = 0; k0 < Cc; k0 += 32) {
        __syncthreads();
        {
            int row = t >> 2, ko = (t & 3) << 3;
            gload16(A + (size_t)(m0 + row) * Cc + k0 + ko, As + t * 8);
            gload16(W + (size_t)(n0 + row) * Cc + k0 + ko, Bs + t * 8);
        }
        __syncthreads();
        bf16x8 af[2], bfr[2];
        #pragma unroll
        for (int i = 0; i < 2; ++i)
            af[i] = *(const bf16x8*)(As + ((wr * 32 + i * 16 + l15) * 32 + l4 * 8));
        #pragma unroll
        for (int j = 0; j < 2; ++j)
            bfr[j] = *(const bf16x8*)(Bs + ((wc * 32 + j * 16 + l15) * 32 + l4 * 8));
        #pragma unroll
        for (int i = 0; i < 2; ++i)
            #pragma unroll
            for (int j = 0; j < 2; ++j)
                acc[i][j] = __builtin_amdgcn_mfma_f32_16x16x32_bf16(af[i], bfr[j], acc[i][j], 0, 0, 0);
    }

    const int r0 = wr * 32 + (l4 << 2);
    const int c0 = wc * 32 + l15;
    #pragma unroll
    for (int i = 0; i < 2; ++i)
        #pragma unroll
        for (int j = 0; j < 2; ++j)
            #pragma unroll
            for (int r = 0; r < 4; ++r)
                outp[(size_t)(m0 + r0 + i * 16 + r) * Cc + n0 + c0 + j * 16] = acc[i][j][r];
}

// ---------------------------------------------------------------------------
// MFMA causal flash attention. K+V LDS dbuf, counted vmcnt(8) (R5-proven).
// Finer split-K: chunk c<8 unsplit, c=8..15 2-way, c>=16 3-way; max job =
// 11 tiles (was 17). 72 LPT-ordered jobs/bh, grid 32x72 = 2304 blocks.
// Job byte = c*4 + p.
// ---------------------------------------------------------------------------
__device__ __constant__ unsigned char JOBS[72] = {
    125,126,122,                                          // 11 tiles
    124,120,121,116,117,118,113,114,110,                  // 10
    112,108,109,104,105,106,101,102, 98,                  // 9
    100, 96, 97, 92, 93, 94, 89, 90, 86, 60, 61, 57, 28,  // 8
     88, 84, 85, 80, 81, 82, 77, 78, 74, 56, 52, 53, 49, 24, // 7
     76, 72, 73, 68, 69, 70, 65, 66, 48, 44, 45, 41, 20,  // 6
     64, 40, 36, 37, 33, 16,                              // 5
     32, 12,                                              // 4
      8,  4,  0                                           // 3,2,1
};

__global__ __launch_bounds__(128)
void attn_mfma(const unsigned short* __restrict__ Q,
               const unsigned short* __restrict__ K,
               const unsigned short* __restrict__ Vt,
               unsigned short* __restrict__ Y,
               unsigned short* __restrict__ P1,   // part-1 partials, rows q>=512
               unsigned short* __restrict__ P2,   // part-2 partials, rows q>=1024
               float* __restrict__ mlf) {         // m[3][32][1536], l[3][32][1536]
    __shared__ unsigned short Ks[2][64 * 64];  // [buf][key][d]   (swizzled)
    __shared__ unsigned short Vs[2][64 * 64];  // [buf][d][key]   (swizzled)

    const int t = threadIdx.x, lane = t & 63, w = t >> 6;
    const int l31 = lane & 31, h = lane >> 5;
    const int bh = blockIdx.x;
    const int bb = bh >> 4, hh = bh & 15;

    const unsigned char job = JOBS[blockIdx.y];
    const int c = job >> 2, p = job & 3;
    const int n = c + 1;
    const int npart = c < 8 ? 1 : (c < 16 ? 2 : 3);
    int kb0, kb1;
    if (npart == 1)      { kb0 = 0;               kb1 = n; }
    else if (npart == 2) { kb0 = p ? n / 2 : 0;   kb1 = p ? n : n / 2; }
    else                 { kb0 = p * n / 3;       kb1 = (p + 1) * n / 3; }

    const int qbase = c * 64 + w * 32;
    const int q = qbase + l31;

    const unsigned short* Qp = Q + (size_t)bh * Tc * Dc;
    const unsigned short* Kp = K + (size_t)bh * Tc * Dc;
    const unsigned short* Vp = Vt + (size_t)bh * Dc * Tc;

    // Q as B-operand: col=q=lane&31, k = kc*16 + h*8 + j  (pre-scaled by 0.125*log2e)
    bf16x8 qf[4];
    #pragma unroll
    for (int kc = 0; kc < 4; ++kc)
        qf[kc] = *(const bf16x8*)(Qp + (size_t)q * 64 + kc * 16 + h * 8);

    f32x16 ot[2] = {};          // O^T: rows d=dt*32+(r&3)+8*(r>>2)+4h, col q
    float m = -INFINITY, lsum = 0.f;

    auto stage = [&](int kb, int buf) {
        #pragma unroll
        for (int it = 0; it < 4; ++it) {
            int idx = t + it * 128;
            int row = idx >> 3, slot = idx & 7;
            int ss = slot ^ (row & 7);  // pre-swizzled source
            gload16(Kp + (size_t)(kb * 64 + row) * 64 + ss * 8, &Ks[buf][idx * 8]);
            gload16(Vp + (size_t)row * Tc + kb * 64 + ss * 8, &Vs[buf][idx * 8]);
        }
    };

    stage(kb0, 0);
    if (kb0 + 1 < kb1) stage(kb0 + 1, 1);

    for (int kb = kb0; kb < kb1; ++kb) {
        const int cur = (kb - kb0) & 1;
        // counted wait: stage(kb) complete, stage(kb+1)'s 8 loads stay in flight
        if (kb + 1 < kb1) asm volatile("s_waitcnt vmcnt(8)" ::: "memory");
        else              asm volatile("s_waitcnt vmcnt(0)" ::: "memory");
        SBAR();

        // ---- S^T = K @ Q^T  (log2 domain; 2 key-tiles of 32) ----
        f32x16 st[2] = {};
        __builtin_amdgcn_s_setprio(1);
        #pragma unroll
        for (int nt = 0; nt < 2; ++nt) {
            int key = nt * 32 + l31;
            #pragma unroll
            for (int kc = 0; kc < 4; ++kc) {
                int boff = (kc * 32 + h * 16) ^ ((key & 7) << 4);
                bf16x8 kf = *(const bf16x8*)(&Ks[cur][((key << 7) + boff) >> 1]);
                st[nt] = __builtin_amdgcn_mfma_f32_32x32x16_bf16(kf, qf[kc], st[nt], 0, 0, 0);
            }
        }
        __builtin_amdgcn_s_setprio(0);

        if (kb * 64 + 63 > qbase) {  // causal mask (diagonal tile only)
            #pragma unroll
            for (int nt = 0; nt < 2; ++nt)
                #pragma unroll
                for (int r = 0; r < 16; ++r) {
                    int key = kb * 64 + nt * 32 + (r & 3) + 8 * (r >> 2) + 4 * h;
                    if (key > q) st[nt][r] = -1e30f;
                }
        }

        // ---- lane-local row max ----
        float mx[16];
        #pragma unroll
        for (int r = 0; r < 16; ++r) mx[r] = fmaxf(st[0][r], st[1][r]);
        #pragma unroll
        for (int s2 = 8; s2 > 0; s2 >>= 1)
            #pragma unroll
            for (int r = 0; r < s2; ++r) mx[r] = fmaxf(mx[r], mx[r + s2]);
        float tmax = fmaxf(mx[0], __shfl_xor(mx[0], 32));

        // ---- defer-max (T13) ----
        if (__any(tmax > m + 8.f)) {
            float mn = fmaxf(m, tmax);
            float al = EXP2(m - mn);
            m = mn;
            lsum *= al;
            #pragma unroll
            for (int dt = 0; dt < 2; ++dt)
                #pragma unroll
                for (int r = 0; r < 16; ++r) ot[dt][r] *= al;
        }

        float psa[4] = {0.f, 0.f, 0.f, 0.f};
        #pragma unroll
        for (int nt = 0; nt < 2; ++nt)
            #pragma unroll
            for (int r = 0; r < 16; ++r) {
                float pv = EXP2(st[nt][r] - m);
                st[nt][r] = pv;
                psa[r & 3] += pv;
            }
        lsum += (psa[0] + psa[1]) + (psa[2] + psa[3]);

        // ---- P^T -> bf16 B-frags in-register (T12), then PV ----
        #pragma unroll
        for (int nt = 0; nt < 2; ++nt) {
            unsigned a0 = cvt_pk_bf16(st[nt][0],  st[nt][1]);
            unsigned b0 = cvt_pk_bf16(st[nt][4],  st[nt][5]);
            unsigned a1 = cvt_pk_bf16(st[nt][2],  st[nt][3]);
            unsigned b1 = cvt_pk_bf16(st[nt][6],  st[nt][7]);
            int2v r0 = __builtin_amdgcn_permlane32_swap((int)a0, (int)b0, false, false);
            int2v r1 = __builtin_amdgcn_permlane32_swap((int)a1, (int)b1, false, false);
            union { unsigned u[4]; bf16x8 v; } pf0, pf1;
            pf0.u[0] = r0.x; pf0.u[1] = r1.x; pf0.u[2] = r0.y; pf0.u[3] = r1.y;
            unsigned c0 = cvt_pk_bf16(st[nt][8],  st[nt][9]);
            unsigned d0 = cvt_pk_bf16(st[nt][12], st[nt][13]);
            unsigned c1 = cvt_pk_bf16(st[nt][10], st[nt][11]);
            unsigned d1 = cvt_pk_bf16(st[nt][14], st[nt][15]);
            int2v r2 = __builtin_amdgcn_permlane32_swap((int)c0, (int)d0, false, false);
            int2v r3 = __builtin_amdgcn_permlane32_swap((int)c1, (int)d1, false, false);
            pf1.u[0] = r2.x; pf1.u[1] = r3.x; pf1.u[2] = r2.y; pf1.u[3] = r3.y;

            __builtin_amdgcn_s_setprio(1);
            #pragma unroll
            for (int dt = 0; dt < 2; ++dt) {
                int d = dt * 32 + l31;
                int v0off = (nt * 64 + h * 16) ^ ((d & 7) << 4);
                bf16x8 vf0 = *(const bf16x8*)(&Vs[cur][((d << 7) + v0off) >> 1]);
                ot[dt] = __builtin_amdgcn_mfma_f32_32x32x16_bf16(vf0, pf0.v, ot[dt], 0, 0, 0);
            }
            #pragma unroll
            for (int dt = 0; dt < 2; ++dt) {
                int d = dt * 32 + l31;
                int v1off = (nt * 64 + 32 + h * 16) ^ ((d & 7) << 4);
                bf16x8 vf1 = *(const bf16x8*)(&Vs[cur][((d << 7) + v1off) >> 1]);
                ot[dt] = __builtin_amdgcn_mfma_f32_32x32x16_bf16(vf1, pf1.v, ot[dt], 0, 0, 0);
            }
            __builtin_amdgcn_s_setprio(0);
        }

        SBAR();                     // all waves done reading buf cur
        if (kb + 2 < kb1) stage(kb + 2, cur);
    }

    // ---- epilogue ----
    float lf = lsum + __shfl_xor(lsum, 32);
    unsigned short* dst;
    size_t base;
    if (npart == 1 || p == 0) {
        dst = Y;  base = ((size_t)bb * Tc + q) * Cc + hh * 64;
    } else if (p == 1) {
        dst = P1; base = ((size_t)(bb * 1536 + (q - 512))) * Cc + hh * 64;
    } else {
        dst = P2; base = ((size_t)(bb * 1024 + (q - 1024))) * Cc + hh * 64;
    }
    float inv = (npart == 1) ? 1.f / lf : 1.f;
    #pragma unroll
    for (int dt = 0; dt < 2; ++dt)
        #pragma unroll
        for (int rg = 0; rg < 4; ++rg) {
            int d0 = dt * 32 + rg * 8 + 4 * h;
            ushort4 s4;
            s4.x = f2bf(ot[dt][rg * 4 + 0] * inv);
            s4.y = f2bf(ot[dt][rg * 4 + 1] * inv);
            s4.z = f2bf(ot[dt][rg * 4 + 2] * inv);
            s4.w = f2bf(ot[dt][rg * 4 + 3] * inv);
            *(ushort4*)(dst + base + d0) = s4;
        }
    if (npart > 1 && h == 0) {
        int mi = p * 49152 + bh * 1536 + (q - 512);
        mlf[mi]          = m;
        mlf[147456 + mi] = lf;
    }
}

// ---------------------------------------------------------------------------
// Combine 2 or 3 split-K partials for rows q in [512, 2048). In-place on Y.
// ---------------------------------------------------------------------------
__global__ __launch_bounds__(256)
void attn_combine(unsigned short* __restrict__ Y,
                  const unsigned short* __restrict__ P1,
                  const unsigned short* __restrict__ P2,
                  const float* __restrict__ mlf) {
    int tid = blockIdx.x * 256 + threadIdx.x;    // 0 .. 393215
    int rowIdx = tid >> 7;                        // bb*1536 + (q-512)
    int col8 = (tid & 127) * 8;
    int bb = rowIdx / 1536, qoff = rowIdx % 1536;
    int q = 512 + qoff;
    int hh = col8 >> 6;
    int mi = (bb * 16 + hh) * 1536 + qoff;
    bool three = q >= 1024;

    float m0 = mlf[mi],          l0 = mlf[147456 + mi];
    float m1 = mlf[49152 + mi],  l1 = mlf[196608 + mi];
    float m2 = three ? mlf[98304 + mi]  : -INFINITY;
    float l2 = three ? mlf[245760 + mi] : 0.f;

    float M = fmaxf(fmaxf(m0, m1), m2);
    float a0 = exp2f(m0 - M), a1 = exp2f(m1 - M);
    float a2 = three ? exp2f(m2 - M) : 0.f;
    float inv = 1.f / (l0 * a0 + l1 * a1 + l2 * a2);

    size_t offY = ((size_t)(bb * Tc + q)) * Cc + col8;
    size_t off1 = ((size_t)rowIdx) * Cc + col8;
    union { unsigned short u[8]; bf16x8 v; } y0, y1, y2, r;
    y0.v = *(const bf16x8*)(Y + offY);
    y1.v = *(const bf16x8*)(P1 + off1);
    if (three) {
        size_t off2 = ((size_t)(bb * 1024 + (q - 1024))) * Cc + col8;
        y2.v = *(const bf16x8*)(P2 + off2);
    }
    #pragma unroll
    for (int j = 0; j < 8; ++j) {
        float acc = bf2f(y0.u[j]) * a0 + bf2f(y1.u[j]) * a1;
        if (three) acc += bf2f(y2.u[j]) * a2;
        r.u[j] = f2bf(acc * inv);
    }
    *(bf16x8*)(Y + offY) = r.v;
}

// ---------------------------------------------------------------------------
extern "C" void kernel_launch(void* const* d_in, const int* in_sizes, int n_in,
                              void* d_out, int out_size, void* d_ws, size_t ws_size,
                              hipStream_t stream) {
    const float* x  = (const float*)d_in[0];
    const float* Wq = (const float*)d_in[1];
    const float* Wk = (const float*)d_in[2];
    const float* Wv = (const float*)d_in[3];
    const float* Wo = (const float*)d_in[4];

    unsigned short* ws = (unsigned short*)d_ws;
    const size_t nX = (size_t)Mc * Cc;   // 4194304
    const size_t nW = (size_t)Cc * Cc;   // 1048576
    size_t off = 0;
    unsigned short* xb  = ws + off; off += nX;   // dead after gemm_qkv -> P1 (6.3MB<=8.4MB)
    unsigned short* Wqb = ws + off; off += nW;   // dead -> P2 (with Wkb, 4.19MB)
    unsigned short* Wkb = ws + off; off += nW;
    unsigned short* Wvb = ws + off; off += nW;   // dead -> mlf (1.18MB<=2.1MB)
    unsigned short* Wob = ws + off; off += nW;   // LIVE until gemm_out
    unsigned short* Qw  = ws + off; off += nX;
    unsigned short* Kw  = ws + off; off += nX;
    unsigned short* Vtw = ws + off; off += nX;
    unsigned short* Yb  = ws + off; off += nX;

    dim3 blk(256);
    cast_bf16<<<dim3((int)(nX / 8 / 256)), blk, 0, stream>>>(x, xb, (int)(nX / 8));
    cast_w4<<<dim3(512, 4), blk, 0, stream>>>(Wq, Wk, Wv, Wo, Wqb, Wkb, Wvb, Wob);

    gemm_qkv<<<dim3(Mc / 128, 24), blk, 0, stream>>>(xb, Wqb, Wkb, Wvb, Qw, Kw, Vtw);

    unsigned short* P1 = xb;
    unsigned short* P2 = Wqb;            // spans Wqb+Wkb
    float* mlf = (float*)Wvb;
    attn_mfma<<<dim3(Bc * Hc, 72), dim3(128), 0, stream>>>(Qw, Kw, Vtw, Yb, P1, P2, mlf);
    attn_combine<<<dim3(1536), blk, 0, stream>>>(Yb, P1, P2, mlf);

    gemm_out<<<dim3(Mc / 64, Cc / 64), blk, 0, stream>>>(Yb, Wob, (float*)d_out);
}

// Round 11
// 114.382 us; speedup vs baseline: 1.1654x; 1.0415x over previous
//
#include <hip/hip_runtime.h>
#include <math.h>

typedef short bf16x8 __attribute__((ext_vector_type(8)));
typedef float f32x4 __attribute__((ext_vector_type(4)));
typedef float f32x16 __attribute__((ext_vector_type(16)));
typedef int int2v __attribute__((ext_vector_type(2)));

constexpr int Bc = 2, Tc = 2048, Cc = 1024, Hc = 16, Dc = 64;
constexpr int Mc = Bc * Tc;  // 4096

#if __has_builtin(__builtin_amdgcn_exp2f)
#define EXP2(x) __builtin_amdgcn_exp2f(x)
#else
#define EXP2(x) exp2f(x)
#endif

#define SBAR() do { asm volatile("" ::: "memory"); \
                    __builtin_amdgcn_s_barrier();   \
                    asm volatile("" ::: "memory"); } while (0)

__device__ __forceinline__ unsigned short f2bf(float f) {
    union { float f; unsigned u; } v; v.f = f;
    unsigned r = v.u + 0x7fffu + ((v.u >> 16) & 1u);  // RNE
    return (unsigned short)(r >> 16);
}

__device__ __forceinline__ float bf2f(unsigned short u) {
    union { unsigned u; float f; } v; v.u = (unsigned)u << 16; return v.f;
}

__device__ __forceinline__ unsigned cvt_pk_bf16(float lo, float hi) {
    unsigned r;
    asm("v_cvt_pk_bf16_f32 %0, %1, %2" : "=v"(r) : "v"(lo), "v"(hi));
    return r;
}

__device__ __forceinline__ void gload16(const void* g, void* l) {
    __builtin_amdgcn_global_load_lds(
        (const __attribute__((address_space(1))) void*)g,
        (__attribute__((address_space(3))) void*)l, 16, 0, 0);
}

// ---------------------------------------------------------------------------
__global__ __launch_bounds__(256)
void cast_bf16(const float* __restrict__ in, unsigned short* __restrict__ out, int n8) {
    int i = blockIdx.x * 256 + threadIdx.x;
    if (i >= n8) return;
    const float4* p = (const float4*)in;
    float4 a = p[i * 2], b = p[i * 2 + 1];
    union { unsigned short u[8]; bf16x8 v; } r;
    r.u[0] = f2bf(a.x); r.u[1] = f2bf(a.y); r.u[2] = f2bf(a.z); r.u[3] = f2bf(a.w);
    r.u[4] = f2bf(b.x); r.u[5] = f2bf(b.y); r.u[6] = f2bf(b.z); r.u[7] = f2bf(b.w);
    *(bf16x8*)(out + i * 8) = r.v;
}

__global__ __launch_bounds__(256)
void cast_w4(const float* __restrict__ a, const float* __restrict__ b,
             const float* __restrict__ c, const float* __restrict__ d,
             unsigned short* __restrict__ oa, unsigned short* __restrict__ ob,
             unsigned short* __restrict__ oc, unsigned short* __restrict__ od) {
    const float* src = blockIdx.y == 0 ? a : blockIdx.y == 1 ? b : blockIdx.y == 2 ? c : d;
    unsigned short* dst = blockIdx.y == 0 ? oa : blockIdx.y == 1 ? ob : blockIdx.y == 2 ? oc : od;
    int i = blockIdx.x * 256 + threadIdx.x;
    const float4* p = (const float4*)src;
    float4 x = p[i * 2], y = p[i * 2 + 1];
    union { unsigned short u[8]; bf16x8 v; } r;
    r.u[0] = f2bf(x.x); r.u[1] = f2bf(x.y); r.u[2] = f2bf(x.z); r.u[3] = f2bf(x.w);
    r.u[4] = f2bf(y.x); r.u[5] = f2bf(y.y); r.u[6] = f2bf(y.z); r.u[7] = f2bf(y.w);
    *(bf16x8*)(dst + i * 8) = r.v;
}

// ---------------------------------------------------------------------------
// Fused QKV GEMM (NT) -- best-known config (R4): 128x128 tile, BK=32,
// 4 waves, single-buffer 2-barrier loop, 768 blocks.
// ---------------------------------------------------------------------------
__global__ __launch_bounds__(256)
void gemm_qkv(const unsigned short* __restrict__ A,
              const unsigned short* __restrict__ Wq,
              const unsigned short* __restrict__ Wk,
              const unsigned short* __restrict__ Wv,
              unsigned short* __restrict__ Qo,
              unsigned short* __restrict__ Ko,
              unsigned short* __restrict__ Vo) {
    __shared__ unsigned short As[128 * 32];
    __shared__ unsigned short Bs[128 * 32];
    const int t = threadIdx.x;
    const int lane = t & 63, l15 = lane & 15, l4 = lane >> 4;
    const int w = t >> 6, wr = w >> 1, wc = w & 1;
    const int seg = blockIdx.y >> 3;              // 0=Q 1=K 2=V
    const unsigned short* W = seg == 0 ? Wq : seg == 1 ? Wk : Wv;
    const int m0 = blockIdx.x * 128, n0 = (blockIdx.y & 7) * 128;

    f32x4 acc[4][4] = {};

    for (int k0 = 0; k0 < Cc; k0 += 32) {
        __syncthreads();
        #pragma unroll
        for (int it = 0; it < 2; ++it) {
            int c = t + it * 256;
            int row = c >> 2, ko = (c & 3) << 3;
            gload16(A + (size_t)(m0 + row) * Cc + k0 + ko, As + c * 8);
            gload16(W + (size_t)(n0 + row) * Cc + k0 + ko, Bs + c * 8);
        }
        __syncthreads();
        bf16x8 af[4], bfr[4];
        #pragma unroll
        for (int i = 0; i < 4; ++i)
            af[i] = *(const bf16x8*)(As + ((wr * 64 + i * 16 + l15) * 32 + l4 * 8));
        #pragma unroll
        for (int j = 0; j < 4; ++j)
            bfr[j] = *(const bf16x8*)(Bs + ((wc * 64 + j * 16 + l15) * 32 + l4 * 8));
        #pragma unroll
        for (int i = 0; i < 4; ++i)
            #pragma unroll
            for (int j = 0; j < 4; ++j)
                acc[i][j] = __builtin_amdgcn_mfma_f32_16x16x32_bf16(af[i], bfr[j], acc[i][j], 0, 0, 0);
    }

    const float qscale = 0.18033688011112042f;  // 0.125 * log2(e)
    const int r0 = wr * 64 + (l4 << 2);
    const int c0 = wc * 64 + l15;
    #pragma unroll
    for (int i = 0; i < 4; ++i)
        #pragma unroll
        for (int j = 0; j < 4; ++j)
            #pragma unroll
            for (int r = 0; r < 4; ++r) {
                int row = m0 + r0 + i * 16 + r;
                int col = n0 + c0 + j * 16;
                float v = acc[i][j][r];
                int bb = row >> 11, tt = row & (Tc - 1);
                int hh = col >> 6, dd = col & 63;
                if (seg == 0)
                    Qo[((((size_t)bb * Hc + hh) * Tc + tt) << 6) + dd] = f2bf(v * qscale);
                else if (seg == 1)
                    Ko[((((size_t)bb * Hc + hh) * Tc + tt) << 6) + dd] = f2bf(v);
                else
                    Vo[(((size_t)bb * Hc + hh) * Dc + dd) * Tc + tt] = f2bf(v);
            }
}

// ---------------------------------------------------------------------------
// Out-projection GEMM (NT): 64x64 tile, 1024 blocks (4/CU), fp32 out [M,C].
// ---------------------------------------------------------------------------
__global__ __launch_bounds__(256)
void gemm_out(const unsigned short* __restrict__ A,
              const unsigned short* __restrict__ W,
              float* __restrict__ outp) {
    __shared__ unsigned short As[64 * 32];
    __shared__ unsigned short Bs[64 * 32];
    const int t = threadIdx.x;
    const int lane = t & 63, l15 = lane & 15, l4 = lane >> 4;
    const int w = t >> 6, wr = w >> 1, wc = w & 1;
    const int m0 = blockIdx.x * 64, n0 = blockIdx.y * 64;

    f32x4 acc[2][2] = {};

    for (int k0 = 0; k0 < Cc; k0 += 32) {
        __syncthreads();
        {
            int row = t >> 2, ko = (t & 3) << 3;
            gload16(A + (size_t)(m0 + row) * Cc + k0 + ko, As + t * 8);
            gload16(W + (size_t)(n0 + row) * Cc + k0 + ko, Bs + t * 8);
        }
        __syncthreads();
        bf16x8 af[2], bfr[2];
        #pragma unroll
        for (int i = 0; i < 2; ++i)
            af[i] = *(const bf16x8*)(As + ((wr * 32 + i * 16 + l15) * 32 + l4 * 8));
        #pragma unroll
        for (int j = 0; j < 2; ++j)
            bfr[j] = *(const bf16x8*)(Bs + ((wc * 32 + j * 16 + l15) * 32 + l4 * 8));
        #pragma unroll
        for (int i = 0; i < 2; ++i)
            #pragma unroll
            for (int j = 0; j < 2; ++j)
                acc[i][j] = __builtin_amdgcn_mfma_f32_16x16x32_bf16(af[i], bfr[j], acc[i][j], 0, 0, 0);
    }

    const int r0 = wr * 32 + (l4 << 2);
    const int c0 = wc * 32 + l15;
    #pragma unroll
    for (int i = 0; i < 2; ++i)
        #pragma unroll
        for (int j = 0; j < 2; ++j)
            #pragma unroll
            for (int r = 0; r < 4; ++r)
                outp[(size_t)(m0 + r0 + i * 16 + r) * Cc + n0 + c0 + j * 16] = acc[i][j][r];
}

// ---------------------------------------------------------------------------
// MFMA causal flash attention. 4 waves x 32 q-rows = 128 rows/block sharing
// one 32 KB K+V dbuf (20 waves/CU LDS cap vs 10 before). Counted vmcnt(4).
// Split-K on 128-row chunks: c<4 unsplit, c=4..9 2-way, c>=10 3-way.
// 34 LPT jobs/bh, grid 32x34. Job byte = c*4 + p.
// ---------------------------------------------------------------------------
__device__ __constant__ unsigned char JOBS[34] = {
    61, 62,                                  // 11 tiles
    60, 56, 57, 58, 54, 36, 37,              // 10
    52, 53, 49, 50, 32, 33,                  // 9
    48, 44, 45, 46, 42, 28, 29, 12,          // 8
    40, 41, 24, 25,                          // 7
    20, 21, 8,                               // 6
    16, 17,                                  // 5
    4, 0                                     // 4, 2
};

__global__ __launch_bounds__(256)
void attn_mfma(const unsigned short* __restrict__ Q,
               const unsigned short* __restrict__ K,
               const unsigned short* __restrict__ Vt,
               unsigned short* __restrict__ Y,
               unsigned short* __restrict__ P1,   // p=1 partials, q in [512,2048)
               unsigned short* __restrict__ P2,   // p=2 partials, q in [1280,2048)
               float* __restrict__ mlf) {         // m[3][32][1536], l[3][32][1536]
    __shared__ unsigned short Ks[2][64 * 64];  // [buf][key][d]   (swizzled)
    __shared__ unsigned short Vs[2][64 * 64];  // [buf][d][key]   (swizzled)

    const int t = threadIdx.x, lane = t & 63, w = t >> 6;   // w = 0..3
    const int l31 = lane & 31, h = lane >> 5;
    const int bh = blockIdx.x;
    const int bb = bh >> 4, hh = bh & 15;

    const unsigned char job = JOBS[blockIdx.y];
    const int c = job >> 2, p = job & 3;
    const int n = 2 * c + 2;                       // tiles in chunk
    const int npart = c < 4 ? 1 : (c < 10 ? 2 : 3);
    const int kb0 = p * n / npart;
    const int kb1 = (p + 1) * n / npart;

    const int qbase = c * 128 + w * 32;
    const int q = qbase + l31;

    const unsigned short* Qp = Q + (size_t)bh * Tc * Dc;
    const unsigned short* Kp = K + (size_t)bh * Tc * Dc;
    const unsigned short* Vp = Vt + (size_t)bh * Dc * Tc;

    // Q as B-operand: col=q=lane&31, k = kc*16 + h*8 + j  (pre-scaled by 0.125*log2e)
    bf16x8 qf[4];
    #pragma unroll
    for (int kc = 0; kc < 4; ++kc)
        qf[kc] = *(const bf16x8*)(Qp + (size_t)q * 64 + kc * 16 + h * 8);

    f32x16 ot[2] = {};          // O^T: rows d=dt*32+(r&3)+8*(r>>2)+4h, col q
    float m = -INFINITY, lsum = 0.f;

    auto stage = [&](int kb, int buf) {
        #pragma unroll
        for (int it = 0; it < 2; ++it) {
            int idx = t + it * 256;           // 0..511
            int row = idx >> 3, slot = idx & 7;
            int ss = slot ^ (row & 7);        // pre-swizzled source
            gload16(Kp + (size_t)(kb * 64 + row) * 64 + ss * 8, &Ks[buf][idx * 8]);
            gload16(Vp + (size_t)row * Tc + kb * 64 + ss * 8, &Vs[buf][idx * 8]);
        }
    };

    stage(kb0, 0);
    if (kb0 + 1 < kb1) stage(kb0 + 1, 1);

    for (int kb = kb0; kb < kb1; ++kb) {
        const int cur = (kb - kb0) & 1;
        // counted wait: stage(kb) done; stage(kb+1)'s 4 loads stay in flight
        if (kb + 1 < kb1) asm volatile("s_waitcnt vmcnt(4)" ::: "memory");
        else              asm volatile("s_waitcnt vmcnt(0)" ::: "memory");
        SBAR();

        // wave-uniform: lower waves skip fully-masked tail tiles of the chunk
        const bool active = (kb * 64 <= qbase + 31);
        if (active) {
            // ---- S^T = K @ Q^T  (log2 domain; 2 key-tiles of 32) ----
            f32x16 st[2] = {};
            __builtin_amdgcn_s_setprio(1);
            #pragma unroll
            for (int nt = 0; nt < 2; ++nt) {
                int key = nt * 32 + l31;
                #pragma unroll
                for (int kc = 0; kc < 4; ++kc) {
                    int boff = (kc * 32 + h * 16) ^ ((key & 7) << 4);
                    bf16x8 kf = *(const bf16x8*)(&Ks[cur][((key << 7) + boff) >> 1]);
                    st[nt] = __builtin_amdgcn_mfma_f32_32x32x16_bf16(kf, qf[kc], st[nt], 0, 0, 0);
                }
            }
            __builtin_amdgcn_s_setprio(0);

            if (kb * 64 + 63 > qbase) {  // causal mask (diagonal region)
                #pragma unroll
                for (int nt = 0; nt < 2; ++nt)
                    #pragma unroll
                    for (int r = 0; r < 16; ++r) {
                        int key = kb * 64 + nt * 32 + (r & 3) + 8 * (r >> 2) + 4 * h;
                        if (key > q) st[nt][r] = -1e30f;
                    }
            }

            // ---- lane-local row max ----
            float mx[16];
            #pragma unroll
            for (int r = 0; r < 16; ++r) mx[r] = fmaxf(st[0][r], st[1][r]);
            #pragma unroll
            for (int s2 = 8; s2 > 0; s2 >>= 1)
                #pragma unroll
                for (int r = 0; r < s2; ++r) mx[r] = fmaxf(mx[r], mx[r + s2]);
            float tmax = fmaxf(mx[0], __shfl_xor(mx[0], 32));

            // ---- defer-max (T13) ----
            if (__any(tmax > m + 8.f)) {
                float mn = fmaxf(m, tmax);
                float al = EXP2(m - mn);
                m = mn;
                lsum *= al;
                #pragma unroll
                for (int dt = 0; dt < 2; ++dt)
                    #pragma unroll
                    for (int r = 0; r < 16; ++r) ot[dt][r] *= al;
            }

            float psa[4] = {0.f, 0.f, 0.f, 0.f};
            #pragma unroll
            for (int nt = 0; nt < 2; ++nt)
                #pragma unroll
                for (int r = 0; r < 16; ++r) {
                    float pv = EXP2(st[nt][r] - m);
                    st[nt][r] = pv;
                    psa[r & 3] += pv;
                }
            lsum += (psa[0] + psa[1]) + (psa[2] + psa[3]);

            // ---- P^T -> bf16 B-frags in-register (T12), then PV ----
            #pragma unroll
            for (int nt = 0; nt < 2; ++nt) {
                unsigned a0 = cvt_pk_bf16(st[nt][0],  st[nt][1]);
                unsigned b0 = cvt_pk_bf16(st[nt][4],  st[nt][5]);
                unsigned a1 = cvt_pk_bf16(st[nt][2],  st[nt][3]);
                unsigned b1 = cvt_pk_bf16(st[nt][6],  st[nt][7]);
                int2v r0 = __builtin_amdgcn_permlane32_swap((int)a0, (int)b0, false, false);
                int2v r1 = __builtin_amdgcn_permlane32_swap((int)a1, (int)b1, false, false);
                union { unsigned u[4]; bf16x8 v; } pf0, pf1;
                pf0.u[0] = r0.x; pf0.u[1] = r1.x; pf0.u[2] = r0.y; pf0.u[3] = r1.y;
                unsigned c0 = cvt_pk_bf16(st[nt][8],  st[nt][9]);
                unsigned d0 = cvt_pk_bf16(st[nt][12], st[nt][13]);
                unsigned c1 = cvt_pk_bf16(st[nt][10], st[nt][11]);
                unsigned d1 = cvt_pk_bf16(st[nt][14], st[nt][15]);
                int2v r2 = __builtin_amdgcn_permlane32_swap((int)c0, (int)d0, false, false);
                int2v r3 = __builtin_amdgcn_permlane32_swap((int)c1, (int)d1, false, false);
                pf1.u[0] = r2.x; pf1.u[1] = r3.x; pf1.u[2] = r2.y; pf1.u[3] = r3.y;

                __builtin_amdgcn_s_setprio(1);
                #pragma unroll
                for (int dt = 0; dt < 2; ++dt) {
                    int d = dt * 32 + l31;
                    int v0off = (nt * 64 + h * 16) ^ ((d & 7) << 4);
                    bf16x8 vf0 = *(const bf16x8*)(&Vs[cur][((d << 7) + v0off) >> 1]);
                    ot[dt] = __builtin_amdgcn_mfma_f32_32x32x16_bf16(vf0, pf0.v, ot[dt], 0, 0, 0);
                }
                #pragma unroll
                for (int dt = 0; dt < 2; ++dt) {
                    int d = dt * 32 + l31;
                    int v1off = (nt * 64 + 32 + h * 16) ^ ((d & 7) << 4);
                    bf16x8 vf1 = *(const bf16x8*)(&Vs[cur][((d << 7) + v1off) >> 1]);
                    ot[dt] = __builtin_amdgcn_mfma_f32_32x32x16_bf16(vf1, pf1.v, ot[dt], 0, 0, 0);
                }
                __builtin_amdgcn_s_setprio(0);
            }
        }

        SBAR();                     // all waves done reading buf cur
        if (kb + 2 < kb1) stage(kb + 2, cur);
    }

    // ---- epilogue ----
    float lf = lsum + __shfl_xor(lsum, 32);
    unsigned short* dst;
    size_t base;
    if (npart == 1 || p == 0) {
        dst = Y;  base = ((size_t)bb * Tc + q) * Cc + hh * 64;
    } else if (p == 1) {
        dst = P1; base = ((size_t)(bb * 1536 + (q - 512))) * Cc + hh * 64;
    } else {
        dst = P2; base = ((size_t)(bb * 768 + (q - 1280))) * Cc + hh * 64;
    }
    float inv = (npart == 1) ? 1.f / lf : 1.f;
    #pragma unroll
    for (int dt = 0; dt < 2; ++dt)
        #pragma unroll
        for (int rg = 0; rg < 4; ++rg) {
            int d0 = dt * 32 + rg * 8 + 4 * h;
            ushort4 s4;
            s4.x = f2bf(ot[dt][rg * 4 + 0] * inv);
            s4.y = f2bf(ot[dt][rg * 4 + 1] * inv);
            s4.z = f2bf(ot[dt][rg * 4 + 2] * inv);
            s4.w = f2bf(ot[dt][rg * 4 + 3] * inv);
            *(ushort4*)(dst + base + d0) = s4;
        }
    if (npart > 1 && h == 0) {
        int mi = p * 49152 + bh * 1536 + (q - 512);
        mlf[mi]          = m;
        mlf[147456 + mi] = lf;
    }
}

// ---------------------------------------------------------------------------
// Combine 2 or 3 split-K partials for rows q in [512, 2048). In-place on Y.
// ---------------------------------------------------------------------------
__global__ __launch_bounds__(256)
void attn_combine(unsigned short* __restrict__ Y,
                  const unsigned short* __restrict__ P1,
                  const unsigned short* __restrict__ P2,
                  const float* __restrict__ mlf) {
    int tid = blockIdx.x * 256 + threadIdx.x;    // 0 .. 393215
    int rowIdx = tid >> 7;                        // bb*1536 + (q-512)
    int col8 = (tid & 127) * 8;
    int bb = rowIdx / 1536, qoff = rowIdx % 1536;
    int q = 512 + qoff;
    int hh = col8 >> 6;
    int mi = (bb * 16 + hh) * 1536 + qoff;
    bool three = q >= 1280;

    float m0 = mlf[mi],          l0 = mlf[147456 + mi];
    float m1 = mlf[49152 + mi],  l1 = mlf[196608 + mi];
    float m2 = three ? mlf[98304 + mi]  : -INFINITY;
    float l2 = three ? mlf[245760 + mi] : 0.f;

    float M = fmaxf(fmaxf(m0, m1), m2);
    float a0 = exp2f(m0 - M), a1 = exp2f(m1 - M);
    float a2 = three ? exp2f(m2 - M) : 0.f;
    float inv = 1.f / (l0 * a0 + l1 * a1 + l2 * a2);

    size_t offY = ((size_t)(bb * Tc + q)) * Cc + col8;
    size_t off1 = ((size_t)rowIdx) * Cc + col8;
    union { unsigned short u[8]; bf16x8 v; } y0, y1, y2, r;
    y0.v = *(const bf16x8*)(Y + offY);
    y1.v = *(const bf16x8*)(P1 + off1);
    if (three) {
        size_t off2 = ((size_t)(bb * 768 + (q - 1280))) * Cc + col8;
        y2.v = *(const bf16x8*)(P2 + off2);
    }
    #pragma unroll
    for (int j = 0; j < 8; ++j) {
        float acc = bf2f(y0.u[j]) * a0 + bf2f(y1.u[j]) * a1;
        if (three) acc += bf2f(y2.u[j]) * a2;
        r.u[j] = f2bf(acc * inv);
    }
    *(bf16x8*)(Y + offY) = r.v;
}

// ---------------------------------------------------------------------------
extern "C" void kernel_launch(void* const* d_in, const int* in_sizes, int n_in,
                              void* d_out, int out_size, void* d_ws, size_t ws_size,
                              hipStream_t stream) {
    const float* x  = (const float*)d_in[0];
    const float* Wq = (const float*)d_in[1];
    const float* Wk = (const float*)d_in[2];
    const float* Wv = (const float*)d_in[3];
    const float* Wo = (const float*)d_in[4];

    unsigned short* ws = (unsigned short*)d_ws;
    const size_t nX = (size_t)Mc * Cc;   // 4194304
    const size_t nW = (size_t)Cc * Cc;   // 1048576
    size_t off = 0;
    unsigned short* xb  = ws + off; off += nX;   // dead after gemm_qkv -> P1 (6.3MB<=8.4MB)
    unsigned short* Wqb = ws + off; off += nW;   // dead -> P2 (with Wkb, 3.1MB<=4.2MB)
    unsigned short* Wkb = ws + off; off += nW;
    unsigned short* Wvb = ws + off; off += nW;   // dead -> mlf (1.18MB<=2.1MB)
    unsigned short* Wob = ws + off; off += nW;   // LIVE until gemm_out
    unsigned short* Qw  = ws + off; off += nX;
    unsigned short* Kw  = ws + off; off += nX;
    unsigned short* Vtw = ws + off; off += nX;
    unsigned short* Yb  = ws + off; off += nX;

    dim3 blk(256);
    cast_bf16<<<dim3((int)(nX / 8 / 256)), blk, 0, stream>>>(x, xb, (int)(nX / 8));
    cast_w4<<<dim3(512, 4), blk, 0, stream>>>(Wq, Wk, Wv, Wo, Wqb, Wkb, Wvb, Wob);

    gemm_qkv<<<dim3(Mc / 128, 24), blk, 0, stream>>>(xb, Wqb, Wkb, Wvb, Qw, Kw, Vtw);

    unsigned short* P1 = xb;
    unsigned short* P2 = Wqb;            // spans Wqb+Wkb
    float* mlf = (float*)Wvb;
    attn_mfma<<<dim3(Bc * Hc, 34), blk, 0, stream>>>(Qw, Kw, Vtw, Yb, P1, P2, mlf);
    attn_combine<<<dim3(1536), blk, 0, stream>>>(Yb, P1, P2, mlf);

    gemm_out<<<dim3(Mc / 64, Cc / 64), blk, 0, stream>>>(Yb, Wob, (float*)d_out);
}